// Round 1
// baseline (1001.229 us; speedup 1.0000x reference)
//
#include <hip/hip_runtime.h>
#include <hip/hip_bf16.h>
#include <math.h>

#define NWRD 2000
#define BB 64
#define CS 128
#define VV 256

// workspace layout (float offsets)
#define WS_H0T   0                       // [512][64]
#define WS_WCODE (WS_H0T + 512*64)       // [64*6000]  == (B*N, 3) row-major
#define WS_VS    (WS_WCODE + 64*6000)    // [256][32]
#define WS_EMB   (WS_VS + 256*32)        // [128000][32]
#define WS_ACT   (WS_EMB + 128000*32)    // [128000]

// ---------------- K1: h0T[k][b] = relu(v @ w2c_w1 + b1), stored transposed
__global__ void k1_h0(const float* __restrict__ v, const float* __restrict__ w1,
                      const float* __restrict__ b1, float* __restrict__ h0T) {
    int b = blockIdx.x, j = threadIdx.x;          // grid 64, block 512
    float s = b1[j];
#pragma unroll
    for (int k = 0; k < 7; k++) s = fmaf(v[b*7 + k], w1[k*512 + j], s);
    h0T[j*64 + b] = fmaxf(s, 0.f);
}

// ---------------- K2: wcode = h0 @ w2c_w2 + b2  -> ws (64 x 6000 row-major)
// thread = (column, b-group of 16); w2 read ~once from HBM.
__global__ __launch_bounds__(256) void k2_wcode(const float* __restrict__ h0T,
        const float* __restrict__ w2, const float* __restrict__ b2,
        float* __restrict__ wcode) {
    int t = threadIdx.x;
    int coll = t & 63, bg = t >> 6;               // 64 cols x 4 b-groups
    int col = blockIdx.x*64 + coll;
    int colc = col < 6000 ? col : 5999;
    float acc[16];
    float bias = b2[colc];
#pragma unroll
    for (int i = 0; i < 16; i++) acc[i] = bias;
    const float4* h4 = (const float4*)h0T;        // [512][64] floats -> k*16+bg*4+s
    for (int k = 0; k < 512; k++) {
        float w = w2[k*6000 + colc];
        float4 a0 = h4[k*16 + bg*4 + 0];
        float4 a1 = h4[k*16 + bg*4 + 1];
        float4 a2 = h4[k*16 + bg*4 + 2];
        float4 a3 = h4[k*16 + bg*4 + 3];
        acc[0]  = fmaf(a0.x, w, acc[0]);  acc[1]  = fmaf(a0.y, w, acc[1]);
        acc[2]  = fmaf(a0.z, w, acc[2]);  acc[3]  = fmaf(a0.w, w, acc[3]);
        acc[4]  = fmaf(a1.x, w, acc[4]);  acc[5]  = fmaf(a1.y, w, acc[5]);
        acc[6]  = fmaf(a1.z, w, acc[6]);  acc[7]  = fmaf(a1.w, w, acc[7]);
        acc[8]  = fmaf(a2.x, w, acc[8]);  acc[9]  = fmaf(a2.y, w, acc[9]);
        acc[10] = fmaf(a2.z, w, acc[10]); acc[11] = fmaf(a2.w, w, acc[11]);
        acc[12] = fmaf(a3.x, w, acc[12]); acc[13] = fmaf(a3.y, w, acc[13]);
        acc[14] = fmaf(a3.z, w, acc[14]); acc[15] = fmaf(a3.w, w, acc[15]);
    }
    if (col < 6000) {
#pragma unroll
        for (int i = 0; i < 16; i++) wcode[(bg*16 + i)*6000 + col] = acc[i];
    }
}

// ---------------- K3: vs = relu(vcode @ vse_w1 + b1) @ vse_w2 + b2   (256x32)
__global__ __launch_bounds__(256) void k3_vs(const float* __restrict__ w1,
        const float* __restrict__ b1, const float* __restrict__ w2,
        const float* __restrict__ b2, float* __restrict__ vs) {
    __shared__ float hs[8][128];
    int t = threadIdx.x;
    int m = t & 127, half = t >> 7;
#pragma unroll
    for (int q = 0; q < 4; q++) {
        int vloc = half*4 + q;
        int v = blockIdx.x*8 + vloc;
        float x = (2.f/15.f)*(float)(v >> 4) - 1.f;
        float y = (2.f/15.f)*(float)(v & 15) - 1.f;
        float h = b1[m] + x*w1[m] + y*w1[128 + m];
        hs[vloc][m] = fmaxf(h, 0.f);
    }
    __syncthreads();
    int vloc = t >> 5, e = t & 31;
    float s = b2[e];
    for (int mm = 0; mm < 128; mm++) s = fmaf(hs[vloc][mm], w2[mm*32 + e], s);
    vs[(blockIdx.x*8 + vloc)*32 + e] = s;
}

// ---------------- K4: fused fc1 -> fc2 -> (fca sigmoid, fce) for 32 rows/block
__global__ __launch_bounds__(256) void k4_mlp(
        const float* __restrict__ wcode,
        const float* __restrict__ fc1_w, const float* __restrict__ fc1_b,
        const float* __restrict__ fc2_w, const float* __restrict__ fc2_b,
        const float* __restrict__ fca_w, const float* __restrict__ fca_b,
        const float* __restrict__ fce_w, const float* __restrict__ fce_b,
        float* __restrict__ emb, float* __restrict__ act) {
    // sbuf aliases: phase1/2: h1T[256][36]; phase3: h2[32][257]
    __shared__ float sbuf[9216];
    __shared__ float wcs[96];
    int t = threadIdx.x;
    int r0 = blockIdx.x * 32;
    if (t < 96) wcs[t] = wcode[r0*3 + t];
    __syncthreads();
    // fc1: thread t = neuron j; h1T[j][r] (pad 36 keeps b128 alignment)
    {
        float wa = fc1_w[t], wb = fc1_w[256 + t], wc = fc1_w[512 + t], bb = fc1_b[t];
#pragma unroll
        for (int r = 0; r < 32; r++) {
            float h = fmaf(wcs[r*3+2], wc, fmaf(wcs[r*3+1], wb, fmaf(wcs[r*3], wa, bb)));
            sbuf[t*36 + r] = fmaxf(h, 0.f);
        }
    }
    __syncthreads();
    // fc2: acc[r] = h2[r][j]
    float acc[32];
#pragma unroll
    for (int r = 0; r < 32; r++) acc[r] = 0.f;
#pragma unroll 2
    for (int i = 0; i < 256; i++) {
        float w = fc2_w[i*256 + t];
        const float4* hp = (const float4*)&sbuf[i*36];
#pragma unroll
        for (int s4 = 0; s4 < 8; s4++) {
            float4 h4 = hp[s4];
            acc[s4*4+0] = fmaf(h4.x, w, acc[s4*4+0]);
            acc[s4*4+1] = fmaf(h4.y, w, acc[s4*4+1]);
            acc[s4*4+2] = fmaf(h4.z, w, acc[s4*4+2]);
            acc[s4*4+3] = fmaf(h4.w, w, acc[s4*4+3]);
        }
    }
    float bj = fc2_b[t];
    __syncthreads();   // all h1T reads complete before aliasing as h2
#pragma unroll
    for (int r = 0; r < 32; r++) sbuf[r*257 + t] = fmaxf(acc[r] + bj, 0.f);
    __syncthreads();
    // fce: thread = (row r, 4-wide e group)
    {
        int rr = t & 31, e4 = t >> 5;
        float4 a4 = *(const float4*)&fce_b[e4*4];
        for (int j = 0; j < 256; j++) {
            float h = sbuf[rr*257 + j];
            float4 w4 = *(const float4*)&fce_w[j*32 + e4*4];
            a4.x = fmaf(h, w4.x, a4.x);
            a4.y = fmaf(h, w4.y, a4.y);
            a4.z = fmaf(h, w4.z, a4.z);
            a4.w = fmaf(h, w4.w, a4.w);
        }
        *(float4*)&emb[(size_t)(r0 + rr)*32 + e4*4] = a4;
    }
    // fca + sigmoid
    if (t < 32) {
        float s = fca_b[0];
        for (int j = 0; j < 256; j++) s = fmaf(sbuf[t*257 + j], fca_w[j], s);
        act[r0 + t] = 1.f / (1.f + __expf(-s));
    }
}

// ---------------- K5: fused relation -> softmax*act -> einsum (bcv,bnv->bcn)
// block = (b, 128-n tile). routeT[v][g] pad 132; vcT[v][c] chunked 32 v's.
#define K5_LDS_FLOATS (256*132 + 32*132 + 128)
#define K5_LDS_BYTES  (K5_LDS_FLOATS*4)
__global__ __launch_bounds__(256) void k5_route_einsum(
        const float* __restrict__ vc, const float* __restrict__ emb,
        const float* __restrict__ act, const float* __restrict__ vs,
        float* __restrict__ out) {
    extern __shared__ float lds[];
    float* routeT = lds;                          // [256][132]
    float* vcT    = lds + 256*132;                // [32][132]
    float* acts   = lds + 256*132 + 32*132;       // [128]
    int t = threadIdx.x;
    int n0 = blockIdx.x * 128;
    int b  = blockIdx.y;
    // ---- Phase A: relation[g][v] = dot32(emb[b,n0+g], vs[v])
    {
        int g = t >> 1, vh = t & 1;
        int n = n0 + g;
        float4 e[8];
        if (n < NWRD) {
            const float4* ep = (const float4*)&emb[(size_t)n*32];
#pragma unroll
            for (int u = 0; u < 8; u++) e[u] = ep[u];
        } else {
#pragma unroll
            for (int u = 0; u < 8; u++) e[u] = make_float4(0.f,0.f,0.f,0.f);
        }
        if (t < 128) acts[t] = (n0 + t < NWRD) ? act[n0 + t] : 0.f;
        for (int vi = 0; vi < 128; vi++) {
            int v = vh*128 + vi;
            const float4* q = (const float4*)&vs[v*32];
            float s = 0.f;
#pragma unroll
            for (int u = 0; u < 8; u++) {
                float4 qq = q[u];
                s = fmaf(e[u].x, qq.x, s); s = fmaf(e[u].y, qq.y, s);
                s = fmaf(e[u].z, qq.z, s); s = fmaf(e[u].w, qq.w, s);
            }
            routeT[v*132 + g] = s;
        }
    }
    __syncthreads();
    // ---- Phase B: per-g softmax over v (wave-parallel), scale by act
    {
        int wv = t >> 6, lane = t & 63;
        for (int gg = wv*32; gg < wv*32 + 32; gg++) {
            float r0 = routeT[lane*132 + gg];
            float r1 = routeT[(lane+64)*132 + gg];
            float r2 = routeT[(lane+128)*132 + gg];
            float r3 = routeT[(lane+192)*132 + gg];
            float m = fmaxf(fmaxf(r0, r1), fmaxf(r2, r3));
#pragma unroll
            for (int off = 32; off >= 1; off >>= 1) m = fmaxf(m, __shfl_xor(m, off));
            float e0 = __expf(r0 - m), e1 = __expf(r1 - m);
            float e2 = __expf(r2 - m), e3 = __expf(r3 - m);
            float s = e0 + e1 + e2 + e3;
#pragma unroll
            for (int off = 32; off >= 1; off >>= 1) s += __shfl_xor(s, off);
            float sc = acts[gg] / s;
            routeT[lane*132 + gg]       = e0*sc;
            routeT[(lane+64)*132 + gg]  = e1*sc;
            routeT[(lane+128)*132 + gg] = e2*sc;
            routeT[(lane+192)*132 + gg] = e3*sc;
        }
    }
    // ---- Phase C: out[b, c, n0+g] = sum_v vc[b,c,v] * route[g][v]
    int cg = t & 15, ng = t >> 4;
    int c0 = cg*8, nb0 = ng*8;
    float accm[64];
#pragma unroll
    for (int i = 0; i < 64; i++) accm[i] = 0.f;
    int vq = t & 7, cb = t >> 3;
    const float* vcb = vc + (size_t)b*CS*VV;
    for (int chunk = 0; chunk < 8; chunk++) {
        __syncthreads();
        int v0 = chunk*32;
#pragma unroll
        for (int cc = 0; cc < 4; cc++) {
            int c = cb + 32*cc;
            float4 d = *(const float4*)&vcb[(size_t)c*VV + v0 + vq*4];
            vcT[(vq*4+0)*132 + c] = d.x;
            vcT[(vq*4+1)*132 + c] = d.y;
            vcT[(vq*4+2)*132 + c] = d.z;
            vcT[(vq*4+3)*132 + c] = d.w;
        }
        __syncthreads();
        for (int vv = 0; vv < 32; vv++) {
            const float4* cp = (const float4*)&vcT[vv*132 + c0];
            const float4* rp = (const float4*)&routeT[(v0+vv)*132 + nb0];
            float4 ca = cp[0], cb4 = cp[1];
            float4 ra = rp[0], rb = rp[1];
            float a8[8] = {ca.x, ca.y, ca.z, ca.w, cb4.x, cb4.y, cb4.z, cb4.w};
            float r8[8] = {ra.x, ra.y, ra.z, ra.w, rb.x, rb.y, rb.z, rb.w};
#pragma unroll
            for (int i = 0; i < 8; i++)
#pragma unroll
                for (int j = 0; j < 8; j++)
                    accm[i*8+j] = fmaf(a8[i], r8[j], accm[i*8+j]);
        }
    }
    int nbase = n0 + nb0;       // multiple of 8; NWRD % 8 == 0 -> single guard
    if (nbase < NWRD) {
#pragma unroll
        for (int i = 0; i < 8; i++) {
            float* op = out + ((size_t)b*CS + (c0+i))*NWRD + nbase;
            *(float4*)op       = make_float4(accm[i*8+0], accm[i*8+1], accm[i*8+2], accm[i*8+3]);
            *(float4*)(op + 4) = make_float4(accm[i*8+4], accm[i*8+5], accm[i*8+6], accm[i*8+7]);
        }
    }
}

extern "C" void kernel_launch(void* const* d_in, const int* in_sizes, int n_in,
                              void* d_out, int out_size, void* d_ws, size_t ws_size,
                              hipStream_t stream) {
    const float* view_cell = (const float*)d_in[0];
    const float* v       = (const float*)d_in[1];
    const float* w2c_w1  = (const float*)d_in[2];
    const float* w2c_b1  = (const float*)d_in[3];
    const float* w2c_w2  = (const float*)d_in[4];
    const float* w2c_b2  = (const float*)d_in[5];
    const float* fc1_w   = (const float*)d_in[6];
    const float* fc1_b   = (const float*)d_in[7];
    const float* fc2_w   = (const float*)d_in[8];
    const float* fc2_b   = (const float*)d_in[9];
    const float* fca_w   = (const float*)d_in[10];
    const float* fca_b   = (const float*)d_in[11];
    const float* fce_w   = (const float*)d_in[12];
    const float* fce_b   = (const float*)d_in[13];
    const float* vse_w1  = (const float*)d_in[14];
    const float* vse_b1  = (const float*)d_in[15];
    const float* vse_w2  = (const float*)d_in[16];
    const float* vse_b2  = (const float*)d_in[17];
    float* ws    = (float*)d_ws;
    float* h0T   = ws + WS_H0T;
    float* wcode = ws + WS_WCODE;
    float* vsb   = ws + WS_VS;
    float* emb   = ws + WS_EMB;
    float* act   = ws + WS_ACT;
    float* out   = (float*)d_out;

    k1_h0<<<64, 512, 0, stream>>>(v, w2c_w1, w2c_b1, h0T);
    k2_wcode<<<94, 256, 0, stream>>>(h0T, w2c_w2, w2c_b2, wcode);
    k3_vs<<<32, 256, 0, stream>>>(vse_w1, vse_b1, vse_w2, vse_b2, vsb);
    k4_mlp<<<4000, 256, 0, stream>>>(wcode, fc1_w, fc1_b, fc2_w, fc2_b,
                                     fca_w, fca_b, fce_w, fce_b, emb, act);
    (void)hipFuncSetAttribute((const void*)k5_route_einsum,
                              hipFuncAttributeMaxDynamicSharedMemorySize,
                              K5_LDS_BYTES);
    dim3 g5(16, 64);
    k5_route_einsum<<<g5, 256, K5_LDS_BYTES, stream>>>(view_cell, emb, act, vsb, out);
}

// Round 2
// 589.223 us; speedup vs baseline: 1.6992x; 1.6992x over previous
//
#include <hip/hip_runtime.h>
#include <hip/hip_bf16.h>
#include <math.h>

#define NWRD 2000
#define BB 64
#define CS 128
#define VV 256

typedef __attribute__((ext_vector_type(8)))  short short8;   // 8 bf16 (4 VGPRs)
typedef __attribute__((ext_vector_type(16))) float f32x16;   // MFMA 32x32 acc

// workspace layout (float offsets)
#define WS_H0T   0                         // [512][64] f32
#define WS_WCODE (WS_H0T + 512*64)         // 64*6000 f32
#define WS_VSB   (WS_WCODE + 64*6000)      // 256*32 bf16 (4096 f32-equiv)
#define WS_EMBB  (WS_VSB + 4096)           // 128000*32 bf16 (2048000 f32-equiv)
#define WS_ACT   (WS_EMBB + 2048000)       // 128000 f32
#define WS_VCB   (WS_ACT + 128000)         // 64*128*256 bf16 (1048576 f32-equiv)

__device__ __forceinline__ unsigned short f2bf(float x) {
    unsigned int u = __float_as_uint(x);
    u += 0x7fffu + ((u >> 16) & 1u);       // round-to-nearest-even
    return (unsigned short)(u >> 16);
}

// ---------------- K0: view_cell fp32 -> bf16 (vcb), same linear layout
__global__ __launch_bounds__(256) void k0_vcb(const float* __restrict__ vc,
                                              unsigned short* __restrict__ vcb) {
    int i = (blockIdx.x * 256 + threadIdx.x) * 8;
    float4 f0 = *(const float4*)(vc + i);
    float4 f1 = *(const float4*)(vc + i + 4);
    union { short8 v; unsigned short u[8]; } o;
    o.u[0] = f2bf(f0.x); o.u[1] = f2bf(f0.y); o.u[2] = f2bf(f0.z); o.u[3] = f2bf(f0.w);
    o.u[4] = f2bf(f1.x); o.u[5] = f2bf(f1.y); o.u[6] = f2bf(f1.z); o.u[7] = f2bf(f1.w);
    *(short8*)(vcb + i) = o.v;
}

// ---------------- K1: h0T[k][b] = relu(v @ w2c_w1 + b1), stored transposed
__global__ void k1_h0(const float* __restrict__ v, const float* __restrict__ w1,
                      const float* __restrict__ b1, float* __restrict__ h0T) {
    int b = blockIdx.x, j = threadIdx.x;          // grid 64, block 512
    float s = b1[j];
#pragma unroll
    for (int k = 0; k < 7; k++) s = fmaf(v[b*7 + k], w1[k*512 + j], s);
    h0T[j*64 + b] = fmaxf(s, 0.f);
}

// ---------------- K2: wcode = h0 @ w2c_w2 + b2  -> ws (64 x 6000 row-major)
__global__ __launch_bounds__(256) void k2_wcode(const float* __restrict__ h0T,
        const float* __restrict__ w2, const float* __restrict__ b2,
        float* __restrict__ wcode) {
    int t = threadIdx.x;
    int coll = t & 63, bg = t >> 6;               // 64 cols x 4 b-groups
    int col = blockIdx.x*64 + coll;
    int colc = col < 6000 ? col : 5999;
    float acc[16];
    float bias = b2[colc];
#pragma unroll
    for (int i = 0; i < 16; i++) acc[i] = bias;
    const float4* h4 = (const float4*)h0T;
    for (int k = 0; k < 512; k++) {
        float w = w2[k*6000 + colc];
        float4 a0 = h4[k*16 + bg*4 + 0];
        float4 a1 = h4[k*16 + bg*4 + 1];
        float4 a2 = h4[k*16 + bg*4 + 2];
        float4 a3 = h4[k*16 + bg*4 + 3];
        acc[0]  = fmaf(a0.x, w, acc[0]);  acc[1]  = fmaf(a0.y, w, acc[1]);
        acc[2]  = fmaf(a0.z, w, acc[2]);  acc[3]  = fmaf(a0.w, w, acc[3]);
        acc[4]  = fmaf(a1.x, w, acc[4]);  acc[5]  = fmaf(a1.y, w, acc[5]);
        acc[6]  = fmaf(a1.z, w, acc[6]);  acc[7]  = fmaf(a1.w, w, acc[7]);
        acc[8]  = fmaf(a2.x, w, acc[8]);  acc[9]  = fmaf(a2.y, w, acc[9]);
        acc[10] = fmaf(a2.z, w, acc[10]); acc[11] = fmaf(a2.w, w, acc[11]);
        acc[12] = fmaf(a3.x, w, acc[12]); acc[13] = fmaf(a3.y, w, acc[13]);
        acc[14] = fmaf(a3.z, w, acc[14]); acc[15] = fmaf(a3.w, w, acc[15]);
    }
    if (col < 6000) {
#pragma unroll
        for (int i = 0; i < 16; i++) wcode[(bg*16 + i)*6000 + col] = acc[i];
    }
}

// ---------------- K3: vs = relu(vcode @ vse_w1 + b1) @ vse_w2 + b2 -> bf16
__global__ __launch_bounds__(256) void k3_vs(const float* __restrict__ w1,
        const float* __restrict__ b1, const float* __restrict__ w2,
        const float* __restrict__ b2, unsigned short* __restrict__ vsb) {
    __shared__ float hs[8][128];
    int t = threadIdx.x;
    int m = t & 127, half = t >> 7;
#pragma unroll
    for (int q = 0; q < 4; q++) {
        int vloc = half*4 + q;
        int v = blockIdx.x*8 + vloc;
        float x = (2.f/15.f)*(float)(v >> 4) - 1.f;
        float y = (2.f/15.f)*(float)(v & 15) - 1.f;
        float h = b1[m] + x*w1[m] + y*w1[128 + m];
        hs[vloc][m] = fmaxf(h, 0.f);
    }
    __syncthreads();
    int vloc = t >> 5, e = t & 31;
    float s = b2[e];
    for (int mm = 0; mm < 128; mm++) s = fmaf(hs[vloc][mm], w2[mm*32 + e], s);
    vsb[(blockIdx.x*8 + vloc)*32 + e] = f2bf(s);
}

// ---------------- K4: fused fc1 -> fc2 -> (fca sigmoid, fce->bf16)
__global__ __launch_bounds__(256) void k4_mlp(
        const float* __restrict__ wcode,
        const float* __restrict__ fc1_w, const float* __restrict__ fc1_b,
        const float* __restrict__ fc2_w, const float* __restrict__ fc2_b,
        const float* __restrict__ fca_w, const float* __restrict__ fca_b,
        const float* __restrict__ fce_w, const float* __restrict__ fce_b,
        unsigned short* __restrict__ embg, float* __restrict__ act) {
    __shared__ float sbuf[9216];
    __shared__ float wcs[96];
    int t = threadIdx.x;
    int r0 = blockIdx.x * 32;
    if (t < 96) wcs[t] = wcode[r0*3 + t];
    __syncthreads();
    {
        float wa = fc1_w[t], wb = fc1_w[256 + t], wc = fc1_w[512 + t], bb = fc1_b[t];
#pragma unroll
        for (int r = 0; r < 32; r++) {
            float h = fmaf(wcs[r*3+2], wc, fmaf(wcs[r*3+1], wb, fmaf(wcs[r*3], wa, bb)));
            sbuf[t*36 + r] = fmaxf(h, 0.f);
        }
    }
    __syncthreads();
    float acc[32];
#pragma unroll
    for (int r = 0; r < 32; r++) acc[r] = 0.f;
#pragma unroll 2
    for (int i = 0; i < 256; i++) {
        float w = fc2_w[i*256 + t];
        const float4* hp = (const float4*)&sbuf[i*36];
#pragma unroll
        for (int s4 = 0; s4 < 8; s4++) {
            float4 h4 = hp[s4];
            acc[s4*4+0] = fmaf(h4.x, w, acc[s4*4+0]);
            acc[s4*4+1] = fmaf(h4.y, w, acc[s4*4+1]);
            acc[s4*4+2] = fmaf(h4.z, w, acc[s4*4+2]);
            acc[s4*4+3] = fmaf(h4.w, w, acc[s4*4+3]);
        }
    }
    float bj = fc2_b[t];
    __syncthreads();
#pragma unroll
    for (int r = 0; r < 32; r++) sbuf[r*257 + t] = fmaxf(acc[r] + bj, 0.f);
    __syncthreads();
    {
        int rr = t & 31, e4 = t >> 5;
        float4 a4 = *(const float4*)&fce_b[e4*4];
        for (int j = 0; j < 256; j++) {
            float h = sbuf[rr*257 + j];
            float4 w4 = *(const float4*)&fce_w[j*32 + e4*4];
            a4.x = fmaf(h, w4.x, a4.x);
            a4.y = fmaf(h, w4.y, a4.y);
            a4.z = fmaf(h, w4.z, a4.z);
            a4.w = fmaf(h, w4.w, a4.w);
        }
        ushort4 o;
        o.x = f2bf(a4.x); o.y = f2bf(a4.y); o.z = f2bf(a4.z); o.w = f2bf(a4.w);
        *(ushort4*)&embg[(size_t)(r0 + rr)*32 + e4*4] = o;
    }
    if (t < 32) {
        float s = fca_b[0];
        for (int j = 0; j < 256; j++) s = fmaf(sbuf[t*257 + j], fca_w[j], s);
        act[r0 + t] = 1.f / (1.f + __expf(-s));
    }
}

// ---------------- K5: MFMA-fused relation -> softmax*act -> einsum
// grid (8 nq, 64 b), 512 threads (8 waves). Per block: 256 n in 2 chunks of 128.
// LDS: routeB [128 n][264 pitch] bf16 (67584 B) + red [8][32] f32 (1024 B).
#define RPITCH 264
#define K5_LDS (128*RPITCH*2 + 8*32*4)
__global__ __launch_bounds__(512, 4) void k5_route_einsum(
        const unsigned short* __restrict__ vcb,
        const unsigned short* __restrict__ embg,
        const float* __restrict__ act,
        const unsigned short* __restrict__ vsb,
        float* __restrict__ out) {
    extern __shared__ char k5lds[];
    unsigned short* routeB = (unsigned short*)k5lds;
    float* red = (float*)(k5lds + 128*RPITCH*2);
    int t = threadIdx.x;
    int w = t >> 6, lane = t & 63, l31 = lane & 31, h = lane >> 5;
    int b = blockIdx.y;
    int basen = blockIdx.x * 256;

    for (int ch = 0; ch < 2; ch++) {
        int n0 = basen + ch * 128;
        // ---- Phase A: relation MFMA (M=v 256, N=n 128, K=32)
        // wave w: n-quarter (w&3)*32, v-half (w>>2)*128
        int nloc = (w & 3) * 32 + l31;
        int vh = w >> 2;
        int nglob = n0 + nloc;
        int embn = b * 2000 + nglob; if (embn > 127999) embn = 127999;
        f32x16 ra[4];
#pragma unroll
        for (int mt = 0; mt < 4; mt++)
#pragma unroll
            for (int i = 0; i < 16; i++) ra[mt][i] = 0.f;
#pragma unroll
        for (int s = 0; s < 2; s++) {
            short8 bfrag = *(const short8*)(embg + (size_t)embn*32 + s*16 + h*8);
#pragma unroll
            for (int mt = 0; mt < 4; mt++) {
                int vrow = (vh*4 + mt)*32 + l31;
                short8 afrag = *(const short8*)(vsb + vrow*32 + s*16 + h*8);
                ra[mt] = __builtin_amdgcn_mfma_f32_32x32x16_bf16(afrag, bfrag, ra[mt], 0, 0, 0);
            }
        }
        // ---- Phase B: softmax over v (per lane: fixed n, 64 v; ^32 lane: +64; ^wave4: +128)
        float mx = -1e30f;
#pragma unroll
        for (int mt = 0; mt < 4; mt++)
#pragma unroll
            for (int i = 0; i < 16; i++) mx = fmaxf(mx, ra[mt][i]);
        mx = fmaxf(mx, __shfl_xor(mx, 32));
        if (lane < 32) red[w*32 + l31] = mx;
        __syncthreads();
        mx = fmaxf(mx, red[(w ^ 4)*32 + l31]);
        float sm = 0.f;
#pragma unroll
        for (int mt = 0; mt < 4; mt++)
#pragma unroll
            for (int i = 0; i < 16; i++) {
                float e = __expf(ra[mt][i] - mx);
                ra[mt][i] = e;
                sm += e;
            }
        sm += __shfl_xor(sm, 32);
        __syncthreads();                       // max reads done before red reuse
        if (lane < 32) red[w*32 + l31] = sm;
        __syncthreads();
        sm += red[(w ^ 4)*32 + l31];
        float scale = act[embn] / sm;
        // write routeB[n][v] bf16
#pragma unroll
        for (int mt = 0; mt < 4; mt++) {
#pragma unroll
            for (int rp = 0; rp < 4; rp++) {
                int vb = vh*128 + mt*32 + rp*8 + h*4;
                unsigned int p0 = (unsigned int)f2bf(ra[mt][rp*4+0]*scale)
                                | ((unsigned int)f2bf(ra[mt][rp*4+1]*scale) << 16);
                unsigned int p1 = (unsigned int)f2bf(ra[mt][rp*4+2]*scale)
                                | ((unsigned int)f2bf(ra[mt][rp*4+3]*scale) << 16);
                *(uint2*)(routeB + nloc*RPITCH + vb) = make_uint2(p0, p1);
            }
        }
        __syncthreads();                       // routeB ready
        // ---- Phase C: out tile (128c x 128n) = vcb (128x256) @ routeB^T
        // wave w: n-tile (w&3), c-tiles {(w>>2)*2, +1}
        {
            int nt = w & 3, mt2 = w >> 2;
            f32x16 c0, c1;
#pragma unroll
            for (int i = 0; i < 16; i++) { c0[i] = 0.f; c1[i] = 0.f; }
            const unsigned short* rrow = routeB + (nt*32 + l31)*RPITCH;
            size_t arow0 = ((size_t)(b*128 + mt2*64 + l31))*256;
            size_t arow1 = arow0 + 32*256;
#pragma unroll 4
            for (int ks = 0; ks < 16; ks++) {
                int k0 = ks*16 + h*8;
                short8 bf = *(const short8*)(rrow + k0);
                short8 a0 = *(const short8*)(vcb + arow0 + k0);
                short8 a1 = *(const short8*)(vcb + arow1 + k0);
                c0 = __builtin_amdgcn_mfma_f32_32x32x16_bf16(a0, bf, c0, 0, 0, 0);
                c1 = __builtin_amdgcn_mfma_f32_32x32x16_bf16(a1, bf, c1, 0, 0, 0);
            }
            int ng = n0 + nt*32 + l31;
            if (ng < NWRD) {
                float* ob = out + (size_t)b*128*NWRD + ng;
#pragma unroll
                for (int i = 0; i < 16; i++) {
                    int crow = (i & 3) + 8*(i >> 2) + 4*h;
                    ob[(size_t)(mt2*64 + crow)*NWRD]      = c0[i];
                    ob[(size_t)(mt2*64 + 32 + crow)*NWRD] = c1[i];
                }
            }
        }
        __syncthreads();                       // before next chunk overwrites routeB
    }
}

extern "C" void kernel_launch(void* const* d_in, const int* in_sizes, int n_in,
                              void* d_out, int out_size, void* d_ws, size_t ws_size,
                              hipStream_t stream) {
    const float* view_cell = (const float*)d_in[0];
    const float* v       = (const float*)d_in[1];
    const float* w2c_w1  = (const float*)d_in[2];
    const float* w2c_b1  = (const float*)d_in[3];
    const float* w2c_w2  = (const float*)d_in[4];
    const float* w2c_b2  = (const float*)d_in[5];
    const float* fc1_w   = (const float*)d_in[6];
    const float* fc1_b   = (const float*)d_in[7];
    const float* fc2_w   = (const float*)d_in[8];
    const float* fc2_b   = (const float*)d_in[9];
    const float* fca_w   = (const float*)d_in[10];
    const float* fca_b   = (const float*)d_in[11];
    const float* fce_w   = (const float*)d_in[12];
    const float* fce_b   = (const float*)d_in[13];
    const float* vse_w1  = (const float*)d_in[14];
    const float* vse_b1  = (const float*)d_in[15];
    const float* vse_w2  = (const float*)d_in[16];
    const float* vse_b2  = (const float*)d_in[17];
    float* ws    = (float*)d_ws;
    float* h0T   = ws + WS_H0T;
    float* wcode = ws + WS_WCODE;
    unsigned short* vsb  = (unsigned short*)(ws + WS_VSB);
    unsigned short* embg = (unsigned short*)(ws + WS_EMBB);
    float* act   = ws + WS_ACT;
    unsigned short* vcb  = (unsigned short*)(ws + WS_VCB);
    float* out   = (float*)d_out;

    k0_vcb<<<1024, 256, 0, stream>>>(view_cell, vcb);
    k1_h0<<<64, 512, 0, stream>>>(v, w2c_w1, w2c_b1, h0T);
    k2_wcode<<<94, 256, 0, stream>>>(h0T, w2c_w2, w2c_b2, wcode);
    k3_vs<<<32, 256, 0, stream>>>(vse_w1, vse_b1, vse_w2, vse_b2, vsb);
    k4_mlp<<<4000, 256, 0, stream>>>(wcode, fc1_w, fc1_b, fc2_w, fc2_b,
                                     fca_w, fca_b, fce_w, fce_b, embg, act);
    (void)hipFuncSetAttribute((const void*)k5_route_einsum,
                              hipFuncAttributeMaxDynamicSharedMemorySize,
                              K5_LDS);
    dim3 g5(8, 64);
    k5_route_einsum<<<g5, 512, K5_LDS, stream>>>(vcb, embg, act, vsb, out);
}

// Round 3
// 354.343 us; speedup vs baseline: 2.8256x; 1.6629x over previous
//
#include <hip/hip_runtime.h>
#include <hip/hip_bf16.h>
#include <math.h>

#define NWRD 2000
#define BB 64
#define CS 128
#define VV 256

typedef __attribute__((ext_vector_type(8)))  short short8;   // 8 bf16 (4 VGPRs)
typedef __attribute__((ext_vector_type(16))) float f32x16;   // MFMA 32x32 acc

// workspace layout (float offsets)
#define WS_H0T   0                         // [512][64] f32; REUSED as fc2wT bf16 after k2
#define WS_WCODE (WS_H0T + 512*64)         // 64*6000 f32
#define WS_VSB   (WS_WCODE + 64*6000)      // 256*32 bf16
#define WS_EMBB  (WS_VSB + 4096)           // 128000*32 bf16
#define WS_ACT   (WS_EMBB + 2048000)       // 128000 f32
#define WS_VCB   (WS_ACT + 128000)         // 64*128*256 bf16
#define WS_FCEWT (WS_VCB + 1048576)        // 32*256 bf16 (transposed fce_w)

__device__ __forceinline__ unsigned short f2bf(float x) {
    unsigned int u = __float_as_uint(x);
    u += 0x7fffu + ((u >> 16) & 1u);       // round-to-nearest-even
    return (unsigned short)(u >> 16);
}

// ---------------- K0: view_cell fp32 -> bf16 (vcb)
__global__ __launch_bounds__(256) void k0_vcb(const float* __restrict__ vc,
                                              unsigned short* __restrict__ vcb) {
    int i = (blockIdx.x * 256 + threadIdx.x) * 8;
    float4 f0 = *(const float4*)(vc + i);
    float4 f1 = *(const float4*)(vc + i + 4);
    union { short8 v; unsigned short u[8]; } o;
    o.u[0] = f2bf(f0.x); o.u[1] = f2bf(f0.y); o.u[2] = f2bf(f0.z); o.u[3] = f2bf(f0.w);
    o.u[4] = f2bf(f1.x); o.u[5] = f2bf(f1.y); o.u[6] = f2bf(f1.z); o.u[7] = f2bf(f1.w);
    *(short8*)(vcb + i) = o.v;
}

// ---------------- K0w: fc2_w (256x256 f32, k-major) -> fc2wT (n-major bf16)
__global__ __launch_bounds__(256) void k0w_fc2t(const float* __restrict__ fc2_w,
                                                unsigned short* __restrict__ fc2wT) {
    __shared__ unsigned short tile[64][72];
    int t = threadIdx.x;
    int k0t = (blockIdx.x >> 2) * 64, n0t = (blockIdx.x & 3) * 64;
    int nl = t & 63, kb = (t >> 6) * 16;
#pragma unroll
    for (int i = 0; i < 16; i++)
        tile[kb + i][nl] = f2bf(fc2_w[(size_t)(k0t + kb + i)*256 + n0t + nl]);
    __syncthreads();
    int kl = t & 63, nb = (t >> 6) * 16;
#pragma unroll
    for (int i = 0; i < 16; i++)
        fc2wT[(size_t)(n0t + nb + i)*256 + k0t + kl] = tile[kl][nb + i];
}

// ---------------- K0e: fce_w (256x32 f32) -> fcewT (32x256 bf16, e-major)
__global__ __launch_bounds__(256) void k0e_fcet(const float* __restrict__ fce_w,
                                                unsigned short* __restrict__ fcewT) {
    int t = threadIdx.x;
    int e = t & 31, kb = (t >> 5) * 32;
    unsigned short tmp[32];
#pragma unroll
    for (int i = 0; i < 32; i++) tmp[i] = f2bf(fce_w[(size_t)(kb + i)*32 + e]);
#pragma unroll
    for (int i = 0; i < 4; i++)
        *(short8*)(fcewT + (size_t)e*256 + kb + i*8) = *(short8*)(tmp + i*8);
}

// ---------------- K1: h0T[k][b] = relu(v @ w2c_w1 + b1), transposed
__global__ void k1_h0(const float* __restrict__ v, const float* __restrict__ w1,
                      const float* __restrict__ b1, float* __restrict__ h0T) {
    int b = blockIdx.x, j = threadIdx.x;
    float s = b1[j];
#pragma unroll
    for (int k = 0; k < 7; k++) s = fmaf(v[b*7 + k], w1[k*512 + j], s);
    h0T[j*64 + b] = fmaxf(s, 0.f);
}

// ---------------- K2: wcode = h0 @ w2c_w2 + b2
__global__ __launch_bounds__(256) void k2_wcode(const float* __restrict__ h0T,
        const float* __restrict__ w2, const float* __restrict__ b2,
        float* __restrict__ wcode) {
    int t = threadIdx.x;
    int coll = t & 63, bg = t >> 6;
    int col = blockIdx.x*64 + coll;
    int colc = col < 6000 ? col : 5999;
    float acc[16];
    float bias = b2[colc];
#pragma unroll
    for (int i = 0; i < 16; i++) acc[i] = bias;
    const float4* h4 = (const float4*)h0T;
    for (int k = 0; k < 512; k++) {
        float w = w2[k*6000 + colc];
        float4 a0 = h4[k*16 + bg*4 + 0];
        float4 a1 = h4[k*16 + bg*4 + 1];
        float4 a2 = h4[k*16 + bg*4 + 2];
        float4 a3 = h4[k*16 + bg*4 + 3];
        acc[0]  = fmaf(a0.x, w, acc[0]);  acc[1]  = fmaf(a0.y, w, acc[1]);
        acc[2]  = fmaf(a0.z, w, acc[2]);  acc[3]  = fmaf(a0.w, w, acc[3]);
        acc[4]  = fmaf(a1.x, w, acc[4]);  acc[5]  = fmaf(a1.y, w, acc[5]);
        acc[6]  = fmaf(a1.z, w, acc[6]);  acc[7]  = fmaf(a1.w, w, acc[7]);
        acc[8]  = fmaf(a2.x, w, acc[8]);  acc[9]  = fmaf(a2.y, w, acc[9]);
        acc[10] = fmaf(a2.z, w, acc[10]); acc[11] = fmaf(a2.w, w, acc[11]);
        acc[12] = fmaf(a3.x, w, acc[12]); acc[13] = fmaf(a3.y, w, acc[13]);
        acc[14] = fmaf(a3.z, w, acc[14]); acc[15] = fmaf(a3.w, w, acc[15]);
    }
    if (col < 6000) {
#pragma unroll
        for (int i = 0; i < 16; i++) wcode[(bg*16 + i)*6000 + col] = acc[i];
    }
}

// ---------------- K3: vs MLP -> bf16
__global__ __launch_bounds__(256) void k3_vs(const float* __restrict__ w1,
        const float* __restrict__ b1, const float* __restrict__ w2,
        const float* __restrict__ b2, unsigned short* __restrict__ vsb) {
    __shared__ float hs[8][128];
    int t = threadIdx.x;
    int m = t & 127, half = t >> 7;
#pragma unroll
    for (int q = 0; q < 4; q++) {
        int vloc = half*4 + q;
        int v = blockIdx.x*8 + vloc;
        float x = (2.f/15.f)*(float)(v >> 4) - 1.f;
        float y = (2.f/15.f)*(float)(v & 15) - 1.f;
        float h = b1[m] + x*w1[m] + y*w1[128 + m];
        hs[vloc][m] = fmaxf(h, 0.f);
    }
    __syncthreads();
    int vloc = t >> 5, e = t & 31;
    float s = b2[e];
    for (int mm = 0; mm < 128; mm++) s = fmaf(hs[vloc][mm], w2[mm*32 + e], s);
    vsb[(blockIdx.x*8 + vloc)*32 + e] = f2bf(s);
}

// ---------------- K4: MFMA MLP. 64 rows/block, 512 threads (8 waves).
// LDS: h1 bf16[64][264] + h2 bf16[64][264] + wcs f32[192] = 68352 B -> 2 blk/CU
#define K4_LDS (64*264*2*2 + 192*4)
__global__ __launch_bounds__(512, 4) void k4_mlp(
        const float* __restrict__ wcode,
        const float* __restrict__ fc1_w, const float* __restrict__ fc1_b,
        const unsigned short* __restrict__ fc2wT, const float* __restrict__ fc2_b,
        const float* __restrict__ fca_w, const float* __restrict__ fca_b,
        const unsigned short* __restrict__ fcewT, const float* __restrict__ fce_b,
        unsigned short* __restrict__ embg, float* __restrict__ act) {
    extern __shared__ char k4lds[];
    unsigned short* h1b = (unsigned short*)k4lds;            // [64][264]
    unsigned short* h2b = (unsigned short*)(k4lds + 33792);  // [64][264]
    float* wcs = (float*)(k4lds + 67584);                    // [192]
    int t = threadIdx.x;
    int w = t >> 6, lane = t & 63, l31 = lane & 31, h = lane >> 5;
    int r0 = blockIdx.x * 64;
    if (t < 192) wcs[t] = wcode[(size_t)r0*3 + t];
    __syncthreads();
    // ---- fc1 (VALU): thread = (4 cols jq, 8 rows rb*8..)
    {
        int jq = (t & 63) * 4, rb = t >> 6;
        float4 wa = *(const float4*)(fc1_w + jq);
        float4 wb = *(const float4*)(fc1_w + 256 + jq);
        float4 wc = *(const float4*)(fc1_w + 512 + jq);
        float4 bb = *(const float4*)(fc1_b + jq);
#pragma unroll
        for (int rr = 0; rr < 8; rr++) {
            int r = rb*8 + rr;
            float c0 = wcs[r*3], c1 = wcs[r*3+1], c2 = wcs[r*3+2];
            float v0 = fmaxf(fmaf(c2, wc.x, fmaf(c1, wb.x, fmaf(c0, wa.x, bb.x))), 0.f);
            float v1 = fmaxf(fmaf(c2, wc.y, fmaf(c1, wb.y, fmaf(c0, wa.y, bb.y))), 0.f);
            float v2 = fmaxf(fmaf(c2, wc.z, fmaf(c1, wb.z, fmaf(c0, wa.z, bb.z))), 0.f);
            float v3 = fmaxf(fmaf(c2, wc.w, fmaf(c1, wb.w, fmaf(c0, wa.w, bb.w))), 0.f);
            uint2 p;
            p.x = (unsigned int)f2bf(v0) | ((unsigned int)f2bf(v1) << 16);
            p.y = (unsigned int)f2bf(v2) | ((unsigned int)f2bf(v3) << 16);
            *(uint2*)(h1b + r*264 + jq) = p;
        }
    }
    __syncthreads();
    // ---- fc2 (MFMA): wave w -> m-tile (w&1), n-tiles (w>>1)*32 and +128
    {
        int mt = w & 1;
        int na = (w >> 1) * 32, nb2 = na + 128;
        f32x16 c0, c1;
#pragma unroll
        for (int i = 0; i < 16; i++) { c0[i] = 0.f; c1[i] = 0.f; }
#pragma unroll 4
        for (int ks = 0; ks < 16; ks++) {
            int k0 = ks*16 + h*8;
            short8 af  = *(const short8*)(h1b + (mt*32 + l31)*264 + k0);
            short8 bfa = *(const short8*)(fc2wT + (size_t)(na  + l31)*256 + k0);
            short8 bfb = *(const short8*)(fc2wT + (size_t)(nb2 + l31)*256 + k0);
            c0 = __builtin_amdgcn_mfma_f32_32x32x16_bf16(af, bfa, c0, 0, 0, 0);
            c1 = __builtin_amdgcn_mfma_f32_32x32x16_bf16(af, bfb, c1, 0, 0, 0);
        }
        float ba = fc2_b[na + l31], bbv = fc2_b[nb2 + l31];
#pragma unroll
        for (int i = 0; i < 16; i++) {
            int row = (i & 3) + 8*(i >> 2) + 4*h;
            h2b[(mt*32 + row)*264 + na  + l31] = f2bf(fmaxf(c0[i] + ba, 0.f));
            h2b[(mt*32 + row)*264 + nb2 + l31] = f2bf(fmaxf(c1[i] + bbv, 0.f));
        }
    }
    __syncthreads();
    // ---- fce (waves 0-1, MFMA) + fca (waves 2-3, VALU)
    if (w < 2) {
        f32x16 ce;
#pragma unroll
        for (int i = 0; i < 16; i++) ce[i] = 0.f;
#pragma unroll 4
        for (int ks = 0; ks < 16; ks++) {
            int k0 = ks*16 + h*8;
            short8 af = *(const short8*)(h2b + (w*32 + l31)*264 + k0);
            short8 bf = *(const short8*)(fcewT + (size_t)l31*256 + k0);
            ce = __builtin_amdgcn_mfma_f32_32x32x16_bf16(af, bf, ce, 0, 0, 0);
        }
        float be = fce_b[l31];
#pragma unroll
        for (int i = 0; i < 16; i++) {
            int row = (i & 3) + 8*(i >> 2) + 4*h;
            int rg = r0 + w*32 + row;
            embg[(size_t)rg*32 + l31] = f2bf(ce[i] + be);
        }
    } else if (w < 4) {
        int t2 = t - 128;
        int row = t2 >> 1, half = t2 & 1;
        float s = half ? 0.f : fca_b[0];
        const unsigned short* hr = h2b + row*264 + half*128;
        const float* wp = fca_w + half*128;
#pragma unroll 8
        for (int kk = 0; kk < 64; kk++) {
            unsigned int u = *(const unsigned int*)(hr + kk*2);
            float lo = __uint_as_float(u << 16);
            float hi = __uint_as_float(u & 0xffff0000u);
            float2 wv = *(const float2*)(wp + kk*2);
            s = fmaf(lo, wv.x, s);
            s = fmaf(hi, wv.y, s);
        }
        s += __shfl_xor(s, 1);
        if (half == 0) act[r0 + row] = 1.f / (1.f + __expf(-s));
    }
}

// ---------------- K5: MFMA-fused relation -> softmax*act -> einsum
#define RPITCH 264
#define K5_LDS (128*RPITCH*2 + 8*32*4)
__global__ __launch_bounds__(512, 4) void k5_route_einsum(
        const unsigned short* __restrict__ vcb,
        const unsigned short* __restrict__ embg,
        const float* __restrict__ act,
        const unsigned short* __restrict__ vsb,
        float* __restrict__ out) {
    extern __shared__ char k5lds[];
    unsigned short* routeB = (unsigned short*)k5lds;
    float* red = (float*)(k5lds + 128*RPITCH*2);
    int t = threadIdx.x;
    int w = t >> 6, lane = t & 63, l31 = lane & 31, h = lane >> 5;
    int b = blockIdx.y;
    int basen = blockIdx.x * 256;

    for (int ch = 0; ch < 2; ch++) {
        int n0 = basen + ch * 128;
        int nloc = (w & 3) * 32 + l31;
        int vh = w >> 2;
        int nglob = n0 + nloc;
        int embn = b * 2000 + nglob; if (embn > 127999) embn = 127999;
        f32x16 ra[4];
#pragma unroll
        for (int mt = 0; mt < 4; mt++)
#pragma unroll
            for (int i = 0; i < 16; i++) ra[mt][i] = 0.f;
#pragma unroll
        for (int s = 0; s < 2; s++) {
            short8 bfrag = *(const short8*)(embg + (size_t)embn*32 + s*16 + h*8);
#pragma unroll
            for (int mt = 0; mt < 4; mt++) {
                int vrow = (vh*4 + mt)*32 + l31;
                short8 afrag = *(const short8*)(vsb + vrow*32 + s*16 + h*8);
                ra[mt] = __builtin_amdgcn_mfma_f32_32x32x16_bf16(afrag, bfrag, ra[mt], 0, 0, 0);
            }
        }
        float mx = -1e30f;
#pragma unroll
        for (int mt = 0; mt < 4; mt++)
#pragma unroll
            for (int i = 0; i < 16; i++) mx = fmaxf(mx, ra[mt][i]);
        mx = fmaxf(mx, __shfl_xor(mx, 32));
        if (lane < 32) red[w*32 + l31] = mx;
        __syncthreads();
        mx = fmaxf(mx, red[(w ^ 4)*32 + l31]);
        float sm = 0.f;
#pragma unroll
        for (int mt = 0; mt < 4; mt++)
#pragma unroll
            for (int i = 0; i < 16; i++) {
                float e = __expf(ra[mt][i] - mx);
                ra[mt][i] = e;
                sm += e;
            }
        sm += __shfl_xor(sm, 32);
        __syncthreads();
        if (lane < 32) red[w*32 + l31] = sm;
        __syncthreads();
        sm += red[(w ^ 4)*32 + l31];
        float scale = act[embn] / sm;
#pragma unroll
        for (int mt = 0; mt < 4; mt++) {
#pragma unroll
            for (int rp = 0; rp < 4; rp++) {
                int vb = vh*128 + mt*32 + rp*8 + h*4;
                unsigned int p0 = (unsigned int)f2bf(ra[mt][rp*4+0]*scale)
                                | ((unsigned int)f2bf(ra[mt][rp*4+1]*scale) << 16);
                unsigned int p1 = (unsigned int)f2bf(ra[mt][rp*4+2]*scale)
                                | ((unsigned int)f2bf(ra[mt][rp*4+3]*scale) << 16);
                *(uint2*)(routeB + nloc*RPITCH + vb) = make_uint2(p0, p1);
            }
        }
        __syncthreads();
        {
            int nt = w & 3, mt2 = w >> 2;
            f32x16 c0, c1;
#pragma unroll
            for (int i = 0; i < 16; i++) { c0[i] = 0.f; c1[i] = 0.f; }
            const unsigned short* rrow = routeB + (nt*32 + l31)*RPITCH;
            size_t arow0 = ((size_t)(b*128 + mt2*64 + l31))*256;
            size_t arow1 = arow0 + 32*256;
#pragma unroll 4
            for (int ks = 0; ks < 16; ks++) {
                int k0 = ks*16 + h*8;
                short8 bf = *(const short8*)(rrow + k0);
                short8 a0 = *(const short8*)(vcb + arow0 + k0);
                short8 a1 = *(const short8*)(vcb + arow1 + k0);
                c0 = __builtin_amdgcn_mfma_f32_32x32x16_bf16(a0, bf, c0, 0, 0, 0);
                c1 = __builtin_amdgcn_mfma_f32_32x32x16_bf16(a1, bf, c1, 0, 0, 0);
            }
            int ng = n0 + nt*32 + l31;
            if (ng < NWRD) {
                float* ob = out + (size_t)b*128*NWRD + ng;
#pragma unroll
                for (int i = 0; i < 16; i++) {
                    int crow = (i & 3) + 8*(i >> 2) + 4*h;
                    ob[(size_t)(mt2*64 + crow)*NWRD]      = c0[i];
                    ob[(size_t)(mt2*64 + 32 + crow)*NWRD] = c1[i];
                }
            }
        }
        __syncthreads();
    }
}

extern "C" void kernel_launch(void* const* d_in, const int* in_sizes, int n_in,
                              void* d_out, int out_size, void* d_ws, size_t ws_size,
                              hipStream_t stream) {
    const float* view_cell = (const float*)d_in[0];
    const float* v       = (const float*)d_in[1];
    const float* w2c_w1  = (const float*)d_in[2];
    const float* w2c_b1  = (const float*)d_in[3];
    const float* w2c_w2  = (const float*)d_in[4];
    const float* w2c_b2  = (const float*)d_in[5];
    const float* fc1_w   = (const float*)d_in[6];
    const float* fc1_b   = (const float*)d_in[7];
    const float* fc2_w   = (const float*)d_in[8];
    const float* fc2_b   = (const float*)d_in[9];
    const float* fca_w   = (const float*)d_in[10];
    const float* fca_b   = (const float*)d_in[11];
    const float* fce_w   = (const float*)d_in[12];
    const float* fce_b   = (const float*)d_in[13];
    const float* vse_w1  = (const float*)d_in[14];
    const float* vse_b1  = (const float*)d_in[15];
    const float* vse_w2  = (const float*)d_in[16];
    const float* vse_b2  = (const float*)d_in[17];
    float* ws    = (float*)d_ws;
    float* h0T   = ws + WS_H0T;
    float* wcode = ws + WS_WCODE;
    unsigned short* vsb   = (unsigned short*)(ws + WS_VSB);
    unsigned short* embg  = (unsigned short*)(ws + WS_EMBB);
    float* act   = ws + WS_ACT;
    unsigned short* vcb   = (unsigned short*)(ws + WS_VCB);
    unsigned short* fc2wT = (unsigned short*)(ws + WS_H0T);    // overlays h0T (dead after k2)
    unsigned short* fcewT = (unsigned short*)(ws + WS_FCEWT);
    float* out   = (float*)d_out;

    k0_vcb<<<1024, 256, 0, stream>>>(view_cell, vcb);
    k1_h0<<<64, 512, 0, stream>>>(v, w2c_w1, w2c_b1, h0T);
    k2_wcode<<<94, 256, 0, stream>>>(h0T, w2c_w2, w2c_b2, wcode);
    k0w_fc2t<<<16, 256, 0, stream>>>(fc2_w, fc2wT);            // after k2: h0T is dead
    k0e_fcet<<<1, 256, 0, stream>>>(fce_w, fcewT);
    k3_vs<<<32, 256, 0, stream>>>(vse_w1, vse_b1, vse_w2, vse_b2, vsb);
    (void)hipFuncSetAttribute((const void*)k4_mlp,
                              hipFuncAttributeMaxDynamicSharedMemorySize, K4_LDS);
    k4_mlp<<<2000, 512, K4_LDS, stream>>>(wcode, fc1_w, fc1_b, fc2wT, fc2_b,
                                          fca_w, fca_b, fcewT, fce_b, embg, act);
    (void)hipFuncSetAttribute((const void*)k5_route_einsum,
                              hipFuncAttributeMaxDynamicSharedMemorySize, K5_LDS);
    dim3 g5(8, 64);
    k5_route_einsum<<<g5, 512, K5_LDS, stream>>>(vcb, embg, act, vsb, out);
}

// Round 4
// 265.793 us; speedup vs baseline: 3.7670x; 1.3332x over previous
//
#include <hip/hip_runtime.h>
#include <hip/hip_bf16.h>
#include <math.h>

#define NWRD 2000
#define BB 64
#define CS 128
#define VV 256

typedef __attribute__((ext_vector_type(8)))  short short8;   // 8 bf16 (4 VGPRs)
typedef __attribute__((ext_vector_type(16))) float f32x16;   // MFMA 32x32 acc

// workspace layout (float offsets)
#define WS_FC2WT 0                         // 256*256 bf16 (32768 f32-equiv)
#define WS_WCODE (WS_FC2WT + 32768)        // 64*6000 f32
#define WS_VSB   (WS_WCODE + 384000)       // 256*32 bf16
#define WS_EMBB  (WS_VSB + 4096)           // 128000*32 bf16; w2T bf16 overlays (dead before k4)
#define WS_ACT   (WS_EMBB + 2048000)       // 128000 f32
#define WS_VCB   (WS_ACT + 128000)         // 64*128*256 bf16
#define WS_FCEWT (WS_VCB + 1048576)        // 32*256 bf16
#define WS_H0B   (WS_FCEWT + 4096)         // 64*512 bf16
#define WS_W2T   WS_EMBB                   // 6000*512 bf16 (1536000 f32-equiv, fits in embg's 2048000)

__device__ __forceinline__ unsigned short f2bf(float x) {
    unsigned int u = __float_as_uint(x);
    u += 0x7fffu + ((u >> 16) & 1u);       // round-to-nearest-even
    return (unsigned short)(u >> 16);
}

// ---------------- K0: view_cell fp32 -> bf16 (vcb)
__global__ __launch_bounds__(256) void k0_vcb(const float* __restrict__ vc,
                                              unsigned short* __restrict__ vcb) {
    int i = (blockIdx.x * 256 + threadIdx.x) * 8;
    float4 f0 = *(const float4*)(vc + i);
    float4 f1 = *(const float4*)(vc + i + 4);
    union { short8 v; unsigned short u[8]; } o;
    o.u[0] = f2bf(f0.x); o.u[1] = f2bf(f0.y); o.u[2] = f2bf(f0.z); o.u[3] = f2bf(f0.w);
    o.u[4] = f2bf(f1.x); o.u[5] = f2bf(f1.y); o.u[6] = f2bf(f1.z); o.u[7] = f2bf(f1.w);
    *(short8*)(vcb + i) = o.v;
}

// ---------------- K0w: fc2_w (256x256 f32, k-major) -> fc2wT (n-major bf16)
__global__ __launch_bounds__(256) void k0w_fc2t(const float* __restrict__ fc2_w,
                                                unsigned short* __restrict__ fc2wT) {
    __shared__ unsigned short tile[64][72];
    int t = threadIdx.x;
    int k0t = (blockIdx.x >> 2) * 64, n0t = (blockIdx.x & 3) * 64;
    int nl = t & 63, kb = (t >> 6) * 16;
#pragma unroll
    for (int i = 0; i < 16; i++)
        tile[kb + i][nl] = f2bf(fc2_w[(size_t)(k0t + kb + i)*256 + n0t + nl]);
    __syncthreads();
    int kl = t & 63, nb = (t >> 6) * 16;
#pragma unroll
    for (int i = 0; i < 16; i++)
        fc2wT[(size_t)(n0t + nb + i)*256 + k0t + kl] = tile[kl][nb + i];
}

// ---------------- K0e: fce_w (256x32 f32) -> fcewT (32x256 bf16, e-major)
__global__ __launch_bounds__(256) void k0e_fcet(const float* __restrict__ fce_w,
                                                unsigned short* __restrict__ fcewT) {
    int t = threadIdx.x;
    int e = t & 31, kb = (t >> 5) * 32;
    unsigned short tmp[32];
#pragma unroll
    for (int i = 0; i < 32; i++) tmp[i] = f2bf(fce_w[(size_t)(kb + i)*32 + e]);
#pragma unroll
    for (int i = 0; i < 4; i++)
        *(short8*)(fcewT + (size_t)e*256 + kb + i*8) = *(short8*)(tmp + i*8);
}

// ---------------- K1: h0b[b][j] = relu(v @ w2c_w1 + b1), bf16 row-major
__global__ void k1_h0(const float* __restrict__ v, const float* __restrict__ w1,
                      const float* __restrict__ b1, unsigned short* __restrict__ h0b) {
    int b = blockIdx.x, j = threadIdx.x;
    float s = b1[j];
#pragma unroll
    for (int k = 0; k < 7; k++) s = fmaf(v[b*7 + k], w1[k*512 + j], s);
    h0b[b*512 + j] = f2bf(fmaxf(s, 0.f));
}

// ---------------- K2t: w2 (512x6000 f32) -> w2T (6000x512 bf16, n-major)
__global__ __launch_bounds__(256) void k2t_w2(const float* __restrict__ w2,
                                              unsigned short* __restrict__ w2T) {
    __shared__ unsigned short tile[64][66];   // [n][k]; pitch 66 -> 2-way (free)
    int t = threadIdx.x;
    int n0 = blockIdx.x * 64;                 // 94 in x
    int k0 = blockIdx.y * 64;                 // 8 in y
    int nl = t & 63, kb = (t >> 6) * 16;
    int nc = (n0 + nl) < 6000 ? (n0 + nl) : 5999;
#pragma unroll
    for (int i = 0; i < 16; i++)
        tile[nl][kb + i] = f2bf(w2[(size_t)(k0 + kb + i)*6000 + nc]);
    __syncthreads();
    int kl = t & 63, nb = (t >> 6) * 16;
#pragma unroll
    for (int i = 0; i < 16; i++) {
        int nn = n0 + nb + i;
        if (nn < 6000) w2T[(size_t)nn*512 + k0 + kl] = tile[nb + i][kl];
    }
}

// ---------------- K2: wcode = h0 @ w2 + b2 via MFMA (M=64, N=6000, K=512)
__global__ __launch_bounds__(512) void k2_gemm(const unsigned short* __restrict__ h0b,
        const unsigned short* __restrict__ w2T, const float* __restrict__ b2,
        float* __restrict__ wcode) {
    int t = threadIdx.x;
    int w = t >> 6, lane = t & 63, l31 = lane & 31, h = lane >> 5;
    int mt = w & 1, nt = w >> 1;              // 2 m-tiles x 4 n-tiles
    int n = blockIdx.x*128 + nt*32 + l31;
    int nc = n < 6000 ? n : 5999;
    f32x16 acc;
#pragma unroll
    for (int i = 0; i < 16; i++) acc[i] = 0.f;
#pragma unroll 8
    for (int ks = 0; ks < 32; ks++) {
        int k0 = ks*16 + h*8;
        short8 af = *(const short8*)(h0b + (mt*32 + l31)*512 + k0);
        short8 bf = *(const short8*)(w2T + (size_t)nc*512 + k0);
        acc = __builtin_amdgcn_mfma_f32_32x32x16_bf16(af, bf, acc, 0, 0, 0);
    }
    if (n < 6000) {
        float bias = b2[n];
#pragma unroll
        for (int i = 0; i < 16; i++) {
            int row = (i & 3) + 8*(i >> 2) + 4*h;
            wcode[(size_t)(mt*32 + row)*6000 + n] = acc[i] + bias;
        }
    }
}

// ---------------- K3: vs MLP -> bf16
__global__ __launch_bounds__(256) void k3_vs(const float* __restrict__ w1,
        const float* __restrict__ b1, const float* __restrict__ w2,
        const float* __restrict__ b2, unsigned short* __restrict__ vsb) {
    __shared__ float hs[8][128];
    int t = threadIdx.x;
    int m = t & 127, half = t >> 7;
#pragma unroll
    for (int q = 0; q < 4; q++) {
        int vloc = half*4 + q;
        int v = blockIdx.x*8 + vloc;
        float x = (2.f/15.f)*(float)(v >> 4) - 1.f;
        float y = (2.f/15.f)*(float)(v & 15) - 1.f;
        float h = b1[m] + x*w1[m] + y*w1[128 + m];
        hs[vloc][m] = fmaxf(h, 0.f);
    }
    __syncthreads();
    int vloc = t >> 5, e = t & 31;
    float s = b2[e];
    for (int mm = 0; mm < 128; mm++) s = fmaf(hs[vloc][mm], w2[mm*32 + e], s);
    vsb[(blockIdx.x*8 + vloc)*32 + e] = f2bf(s);
}

// ---------------- K4: MFMA MLP. 64 rows/block, 512 threads (8 waves).
#define K4_LDS (64*264*2*2 + 192*4)
__global__ __launch_bounds__(512, 4) void k4_mlp(
        const float* __restrict__ wcode,
        const float* __restrict__ fc1_w, const float* __restrict__ fc1_b,
        const unsigned short* __restrict__ fc2wT, const float* __restrict__ fc2_b,
        const float* __restrict__ fca_w, const float* __restrict__ fca_b,
        const unsigned short* __restrict__ fcewT, const float* __restrict__ fce_b,
        unsigned short* __restrict__ embg, float* __restrict__ act) {
    extern __shared__ char k4lds[];
    unsigned short* h1b = (unsigned short*)k4lds;            // [64][264]
    unsigned short* h2b = (unsigned short*)(k4lds + 33792);  // [64][264]
    float* wcs = (float*)(k4lds + 67584);                    // [192]
    int t = threadIdx.x;
    int w = t >> 6, lane = t & 63, l31 = lane & 31, h = lane >> 5;
    int r0 = blockIdx.x * 64;
    if (t < 192) wcs[t] = wcode[(size_t)r0*3 + t];
    __syncthreads();
    {
        int jq = (t & 63) * 4, rb = t >> 6;
        float4 wa = *(const float4*)(fc1_w + jq);
        float4 wb = *(const float4*)(fc1_w + 256 + jq);
        float4 wc = *(const float4*)(fc1_w + 512 + jq);
        float4 bb = *(const float4*)(fc1_b + jq);
#pragma unroll
        for (int rr = 0; rr < 8; rr++) {
            int r = rb*8 + rr;
            float c0 = wcs[r*3], c1 = wcs[r*3+1], c2 = wcs[r*3+2];
            float v0 = fmaxf(fmaf(c2, wc.x, fmaf(c1, wb.x, fmaf(c0, wa.x, bb.x))), 0.f);
            float v1 = fmaxf(fmaf(c2, wc.y, fmaf(c1, wb.y, fmaf(c0, wa.y, bb.y))), 0.f);
            float v2 = fmaxf(fmaf(c2, wc.z, fmaf(c1, wb.z, fmaf(c0, wa.z, bb.z))), 0.f);
            float v3 = fmaxf(fmaf(c2, wc.w, fmaf(c1, wb.w, fmaf(c0, wa.w, bb.w))), 0.f);
            uint2 p;
            p.x = (unsigned int)f2bf(v0) | ((unsigned int)f2bf(v1) << 16);
            p.y = (unsigned int)f2bf(v2) | ((unsigned int)f2bf(v3) << 16);
            *(uint2*)(h1b + r*264 + jq) = p;
        }
    }
    __syncthreads();
    {
        int mt = w & 1;
        int na = (w >> 1) * 32, nb2 = na + 128;
        f32x16 c0, c1;
#pragma unroll
        for (int i = 0; i < 16; i++) { c0[i] = 0.f; c1[i] = 0.f; }
#pragma unroll 4
        for (int ks = 0; ks < 16; ks++) {
            int k0 = ks*16 + h*8;
            short8 af  = *(const short8*)(h1b + (mt*32 + l31)*264 + k0);
            short8 bfa = *(const short8*)(fc2wT + (size_t)(na  + l31)*256 + k0);
            short8 bfb = *(const short8*)(fc2wT + (size_t)(nb2 + l31)*256 + k0);
            c0 = __builtin_amdgcn_mfma_f32_32x32x16_bf16(af, bfa, c0, 0, 0, 0);
            c1 = __builtin_amdgcn_mfma_f32_32x32x16_bf16(af, bfb, c1, 0, 0, 0);
        }
        float ba = fc2_b[na + l31], bbv = fc2_b[nb2 + l31];
#pragma unroll
        for (int i = 0; i < 16; i++) {
            int row = (i & 3) + 8*(i >> 2) + 4*h;
            h2b[(mt*32 + row)*264 + na  + l31] = f2bf(fmaxf(c0[i] + ba, 0.f));
            h2b[(mt*32 + row)*264 + nb2 + l31] = f2bf(fmaxf(c1[i] + bbv, 0.f));
        }
    }
    __syncthreads();
    if (w < 2) {
        f32x16 ce;
#pragma unroll
        for (int i = 0; i < 16; i++) ce[i] = 0.f;
#pragma unroll 4
        for (int ks = 0; ks < 16; ks++) {
            int k0 = ks*16 + h*8;
            short8 af = *(const short8*)(h2b + (w*32 + l31)*264 + k0);
            short8 bf = *(const short8*)(fcewT + (size_t)l31*256 + k0);
            ce = __builtin_amdgcn_mfma_f32_32x32x16_bf16(af, bf, ce, 0, 0, 0);
        }
        float be = fce_b[l31];
#pragma unroll
        for (int i = 0; i < 16; i++) {
            int row = (i & 3) + 8*(i >> 2) + 4*h;
            int rg = r0 + w*32 + row;
            embg[(size_t)rg*32 + l31] = f2bf(ce[i] + be);
        }
    } else if (w < 4) {
        int t2 = t - 128;
        int row = t2 >> 1, half = t2 & 1;
        float s = half ? 0.f : fca_b[0];
        const unsigned short* hr = h2b + row*264 + half*128;
        const float* wp = fca_w + half*128;
#pragma unroll 8
        for (int kk = 0; kk < 64; kk++) {
            unsigned int u = *(const unsigned int*)(hr + kk*2);
            float lo = __uint_as_float(u << 16);
            float hi = __uint_as_float(u & 0xffff0000u);
            float2 wv = *(const float2*)(wp + kk*2);
            s = fmaf(lo, wv.x, s);
            s = fmaf(hi, wv.y, s);
        }
        s += __shfl_xor(s, 1);
        if (half == 0) act[r0 + row] = 1.f / (1.f + __expf(-s));
    }
}

// ---------------- K5: MFMA-fused relation -> softmax*act -> einsum
#define RPITCH 264
#define K5_LDS (128*RPITCH*2 + 8*32*4)
__global__ __launch_bounds__(512, 4) void k5_route_einsum(
        const unsigned short* __restrict__ vcb,
        const unsigned short* __restrict__ embg,
        const float* __restrict__ act,
        const unsigned short* __restrict__ vsb,
        float* __restrict__ out) {
    extern __shared__ char k5lds[];
    unsigned short* routeB = (unsigned short*)k5lds;
    float* red = (float*)(k5lds + 128*RPITCH*2);
    int t = threadIdx.x;
    int w = t >> 6, lane = t & 63, l31 = lane & 31, h = lane >> 5;
    int b = blockIdx.y;
    int basen = blockIdx.x * 256;

    for (int ch = 0; ch < 2; ch++) {
        int n0 = basen + ch * 128;
        int nloc = (w & 3) * 32 + l31;
        int vh = w >> 2;
        int nglob = n0 + nloc;
        int embn = b * 2000 + nglob; if (embn > 127999) embn = 127999;
        f32x16 ra[4];
#pragma unroll
        for (int mt = 0; mt < 4; mt++)
#pragma unroll
            for (int i = 0; i < 16; i++) ra[mt][i] = 0.f;
#pragma unroll
        for (int s = 0; s < 2; s++) {
            short8 bfrag = *(const short8*)(embg + (size_t)embn*32 + s*16 + h*8);
#pragma unroll
            for (int mt = 0; mt < 4; mt++) {
                int vrow = (vh*4 + mt)*32 + l31;
                short8 afrag = *(const short8*)(vsb + vrow*32 + s*16 + h*8);
                ra[mt] = __builtin_amdgcn_mfma_f32_32x32x16_bf16(afrag, bfrag, ra[mt], 0, 0, 0);
            }
        }
        float mx = -1e30f;
#pragma unroll
        for (int mt = 0; mt < 4; mt++)
#pragma unroll
            for (int i = 0; i < 16; i++) mx = fmaxf(mx, ra[mt][i]);
        mx = fmaxf(mx, __shfl_xor(mx, 32));
        if (lane < 32) red[w*32 + l31] = mx;
        __syncthreads();
        mx = fmaxf(mx, red[(w ^ 4)*32 + l31]);
        float sm = 0.f;
#pragma unroll
        for (int mt = 0; mt < 4; mt++)
#pragma unroll
            for (int i = 0; i < 16; i++) {
                float e = __expf(ra[mt][i] - mx);
                ra[mt][i] = e;
                sm += e;
            }
        sm += __shfl_xor(sm, 32);
        __syncthreads();
        if (lane < 32) red[w*32 + l31] = sm;
        __syncthreads();
        sm += red[(w ^ 4)*32 + l31];
        float scale = act[embn] / sm;
#pragma unroll
        for (int mt = 0; mt < 4; mt++) {
#pragma unroll
            for (int rp = 0; rp < 4; rp++) {
                int vb = vh*128 + mt*32 + rp*8 + h*4;
                unsigned int p0 = (unsigned int)f2bf(ra[mt][rp*4+0]*scale)
                                | ((unsigned int)f2bf(ra[mt][rp*4+1]*scale) << 16);
                unsigned int p1 = (unsigned int)f2bf(ra[mt][rp*4+2]*scale)
                                | ((unsigned int)f2bf(ra[mt][rp*4+3]*scale) << 16);
                *(uint2*)(routeB + nloc*RPITCH + vb) = make_uint2(p0, p1);
            }
        }
        __syncthreads();
        {
            int nt = w & 3, mt2 = w >> 2;
            f32x16 c0, c1;
#pragma unroll
            for (int i = 0; i < 16; i++) { c0[i] = 0.f; c1[i] = 0.f; }
            const unsigned short* rrow = routeB + (nt*32 + l31)*RPITCH;
            size_t arow0 = ((size_t)(b*128 + mt2*64 + l31))*256;
            size_t arow1 = arow0 + 32*256;
#pragma unroll 4
            for (int ks = 0; ks < 16; ks++) {
                int k0 = ks*16 + h*8;
                short8 bf = *(const short8*)(rrow + k0);
                short8 a0 = *(const short8*)(vcb + arow0 + k0);
                short8 a1 = *(const short8*)(vcb + arow1 + k0);
                c0 = __builtin_amdgcn_mfma_f32_32x32x16_bf16(a0, bf, c0, 0, 0, 0);
                c1 = __builtin_amdgcn_mfma_f32_32x32x16_bf16(a1, bf, c1, 0, 0, 0);
            }
            int ng = n0 + nt*32 + l31;
            if (ng < NWRD) {
                float* ob = out + (size_t)b*128*NWRD + ng;
#pragma unroll
                for (int i = 0; i < 16; i++) {
                    int crow = (i & 3) + 8*(i >> 2) + 4*h;
                    ob[(size_t)(mt2*64 + crow)*NWRD]      = c0[i];
                    ob[(size_t)(mt2*64 + 32 + crow)*NWRD] = c1[i];
                }
            }
        }
        __syncthreads();
    }
}

extern "C" void kernel_launch(void* const* d_in, const int* in_sizes, int n_in,
                              void* d_out, int out_size, void* d_ws, size_t ws_size,
                              hipStream_t stream) {
    const float* view_cell = (const float*)d_in[0];
    const float* v       = (const float*)d_in[1];
    const float* w2c_w1  = (const float*)d_in[2];
    const float* w2c_b1  = (const float*)d_in[3];
    const float* w2c_w2  = (const float*)d_in[4];
    const float* w2c_b2  = (const float*)d_in[5];
    const float* fc1_w   = (const float*)d_in[6];
    const float* fc1_b   = (const float*)d_in[7];
    const float* fc2_w   = (const float*)d_in[8];
    const float* fc2_b   = (const float*)d_in[9];
    const float* fca_w   = (const float*)d_in[10];
    const float* fca_b   = (const float*)d_in[11];
    const float* fce_w   = (const float*)d_in[12];
    const float* fce_b   = (const float*)d_in[13];
    const float* vse_w1  = (const float*)d_in[14];
    const float* vse_b1  = (const float*)d_in[15];
    const float* vse_w2  = (const float*)d_in[16];
    const float* vse_b2  = (const float*)d_in[17];
    float* ws    = (float*)d_ws;
    unsigned short* fc2wT = (unsigned short*)(ws + WS_FC2WT);
    float* wcode = ws + WS_WCODE;
    unsigned short* vsb   = (unsigned short*)(ws + WS_VSB);
    unsigned short* embg  = (unsigned short*)(ws + WS_EMBB);
    float* act   = ws + WS_ACT;
    unsigned short* vcb   = (unsigned short*)(ws + WS_VCB);
    unsigned short* fcewT = (unsigned short*)(ws + WS_FCEWT);
    unsigned short* h0b   = (unsigned short*)(ws + WS_H0B);
    unsigned short* w2T   = (unsigned short*)(ws + WS_W2T);  // overlays embg (dead until k4)
    float* out   = (float*)d_out;

    k0_vcb<<<1024, 256, 0, stream>>>(view_cell, vcb);
    k1_h0<<<64, 512, 0, stream>>>(v, w2c_w1, w2c_b1, h0b);
    {
        dim3 gt(94, 8);
        k2t_w2<<<gt, 256, 0, stream>>>(w2c_w2, w2T);
    }
    k2_gemm<<<47, 512, 0, stream>>>(h0b, w2T, w2c_b2, wcode);
    k0w_fc2t<<<16, 256, 0, stream>>>(fc2_w, fc2wT);
    k0e_fcet<<<1, 256, 0, stream>>>(fce_w, fcewT);
    k3_vs<<<32, 256, 0, stream>>>(vse_w1, vse_b1, vse_w2, vse_b2, vsb);
    (void)hipFuncSetAttribute((const void*)k4_mlp,
                              hipFuncAttributeMaxDynamicSharedMemorySize, K4_LDS);
    k4_mlp<<<2000, 512, K4_LDS, stream>>>(wcode, fc1_w, fc1_b, fc2wT, fc2_b,
                                          fca_w, fca_b, fcewT, fce_b, embg, act);
    (void)hipFuncSetAttribute((const void*)k5_route_einsum,
                              hipFuncAttributeMaxDynamicSharedMemorySize, K5_LDS);
    dim3 g5(8, 64);
    k5_route_einsum<<<g5, 512, K5_LDS, stream>>>(vcb, embg, act, vsb, out);
}

// Round 5
// 253.610 us; speedup vs baseline: 3.9479x; 1.0480x over previous
//
#include <hip/hip_runtime.h>
#include <hip/hip_bf16.h>
#include <math.h>

#define NWRD 2000
#define BB 64
#define CS 128
#define VV 256

typedef __attribute__((ext_vector_type(8)))  short short8;   // 8 bf16 (4 VGPRs)
typedef __attribute__((ext_vector_type(16))) float f32x16;   // MFMA 32x32 acc

// workspace layout (float offsets)
#define WS_FC2WT 0                         // 256*256 bf16
#define WS_WCODE (WS_FC2WT + 32768)        // 64*6000 f32  ([b][n*3+c])
#define WS_VSB   (WS_WCODE + 384000)       // 256*32 bf16
#define WS_EMBB  (WS_VSB + 4096)           // region reused by w2T bf16
#define WS_ACT   (WS_EMBB + 2048000)       // (unused now)
#define WS_VCB   (WS_ACT + 128000)         // 64*128*256 bf16
#define WS_FCEWT (WS_VCB + 1048576)        // 32*256 bf16
#define WS_H0B   (WS_FCEWT + 4096)         // 64*512 bf16
#define WS_W2T   WS_EMBB                   // 6000*512 bf16

__device__ __forceinline__ unsigned short f2bf(float x) {
    unsigned int u = __float_as_uint(x);
    u += 0x7fffu + ((u >> 16) & 1u);       // round-to-nearest-even
    return (unsigned short)(u >> 16);
}

// ---------------- K0: view_cell fp32 -> bf16 (vcb)
__global__ __launch_bounds__(256) void k0_vcb(const float* __restrict__ vc,
                                              unsigned short* __restrict__ vcb) {
    int i = (blockIdx.x * 256 + threadIdx.x) * 8;
    float4 f0 = *(const float4*)(vc + i);
    float4 f1 = *(const float4*)(vc + i + 4);
    union { short8 v; unsigned short u[8]; } o;
    o.u[0] = f2bf(f0.x); o.u[1] = f2bf(f0.y); o.u[2] = f2bf(f0.z); o.u[3] = f2bf(f0.w);
    o.u[4] = f2bf(f1.x); o.u[5] = f2bf(f1.y); o.u[6] = f2bf(f1.z); o.u[7] = f2bf(f1.w);
    *(short8*)(vcb + i) = o.v;
}

// ---------------- K0w: fc2_w (256x256 f32, k-major) -> fc2wT (n-major bf16)
__global__ __launch_bounds__(256) void k0w_fc2t(const float* __restrict__ fc2_w,
                                                unsigned short* __restrict__ fc2wT) {
    __shared__ unsigned short tile[64][72];
    int t = threadIdx.x;
    int k0t = (blockIdx.x >> 2) * 64, n0t = (blockIdx.x & 3) * 64;
    int nl = t & 63, kb = (t >> 6) * 16;
#pragma unroll
    for (int i = 0; i < 16; i++)
        tile[kb + i][nl] = f2bf(fc2_w[(size_t)(k0t + kb + i)*256 + n0t + nl]);
    __syncthreads();
    int kl = t & 63, nb = (t >> 6) * 16;
#pragma unroll
    for (int i = 0; i < 16; i++)
        fc2wT[(size_t)(n0t + nb + i)*256 + k0t + kl] = tile[kl][nb + i];
}

// ---------------- K0e: fce_w (256x32 f32) -> fcewT (32x256 bf16, e-major)
__global__ __launch_bounds__(256) void k0e_fcet(const float* __restrict__ fce_w,
                                                unsigned short* __restrict__ fcewT) {
    int t = threadIdx.x;
    int e = t & 31, kb = (t >> 5) * 32;
    unsigned short tmp[32];
#pragma unroll
    for (int i = 0; i < 32; i++) tmp[i] = f2bf(fce_w[(size_t)(kb + i)*32 + e]);
#pragma unroll
    for (int i = 0; i < 4; i++)
        *(short8*)(fcewT + (size_t)e*256 + kb + i*8) = *(short8*)(tmp + i*8);
}

// ---------------- K1: h0b[b][j] = relu(v @ w2c_w1 + b1), bf16 row-major
__global__ void k1_h0(const float* __restrict__ v, const float* __restrict__ w1,
                      const float* __restrict__ b1, unsigned short* __restrict__ h0b) {
    int b = blockIdx.x, j = threadIdx.x;
    float s = b1[j];
#pragma unroll
    for (int k = 0; k < 7; k++) s = fmaf(v[b*7 + k], w1[k*512 + j], s);
    h0b[b*512 + j] = f2bf(fmaxf(s, 0.f));
}

// ---------------- K2t: w2 (512x6000 f32) -> w2T (6000x512 bf16, n-major)
__global__ __launch_bounds__(256) void k2t_w2(const float* __restrict__ w2,
                                              unsigned short* __restrict__ w2T) {
    __shared__ unsigned short tile[64][66];
    int t = threadIdx.x;
    int n0 = blockIdx.x * 64;
    int k0 = blockIdx.y * 64;
    int nl = t & 63, kb = (t >> 6) * 16;
    int nc = (n0 + nl) < 6000 ? (n0 + nl) : 5999;
#pragma unroll
    for (int i = 0; i < 16; i++)
        tile[nl][kb + i] = f2bf(w2[(size_t)(k0 + kb + i)*6000 + nc]);
    __syncthreads();
    int kl = t & 63, nb = (t >> 6) * 16;
#pragma unroll
    for (int i = 0; i < 16; i++) {
        int nn = n0 + nb + i;
        if (nn < 6000) w2T[(size_t)nn*512 + k0 + kl] = tile[nb + i][kl];
    }
}

// ---------------- K2: wcode = h0 @ w2 + b2 via MFMA (M=64, N=6000, K=512)
__global__ __launch_bounds__(512) void k2_gemm(const unsigned short* __restrict__ h0b,
        const unsigned short* __restrict__ w2T, const float* __restrict__ b2,
        float* __restrict__ wcode) {
    int t = threadIdx.x;
    int w = t >> 6, lane = t & 63, l31 = lane & 31, h = lane >> 5;
    int mt = w & 1, nt = w >> 1;
    int n = blockIdx.x*128 + nt*32 + l31;
    int nc = n < 6000 ? n : 5999;
    f32x16 acc;
#pragma unroll
    for (int i = 0; i < 16; i++) acc[i] = 0.f;
#pragma unroll 8
    for (int ks = 0; ks < 32; ks++) {
        int k0 = ks*16 + h*8;
        short8 af = *(const short8*)(h0b + (mt*32 + l31)*512 + k0);
        short8 bf = *(const short8*)(w2T + (size_t)nc*512 + k0);
        acc = __builtin_amdgcn_mfma_f32_32x32x16_bf16(af, bf, acc, 0, 0, 0);
    }
    if (n < 6000) {
        float bias = b2[n];
#pragma unroll
        for (int i = 0; i < 16; i++) {
            int row = (i & 3) + 8*(i >> 2) + 4*h;
            wcode[(size_t)(mt*32 + row)*6000 + n] = acc[i] + bias;
        }
    }
}

// ---------------- K3: vs MLP -> bf16
__global__ __launch_bounds__(256) void k3_vs(const float* __restrict__ w1,
        const float* __restrict__ b1, const float* __restrict__ w2,
        const float* __restrict__ b2, unsigned short* __restrict__ vsb) {
    __shared__ float hs[8][128];
    int t = threadIdx.x;
    int m = t & 127, half = t >> 7;
#pragma unroll
    for (int q = 0; q < 4; q++) {
        int vloc = half*4 + q;
        int v = blockIdx.x*8 + vloc;
        float x = (2.f/15.f)*(float)(v >> 4) - 1.f;
        float y = (2.f/15.f)*(float)(v & 15) - 1.f;
        float h = b1[m] + x*w1[m] + y*w1[128 + m];
        hs[vloc][m] = fmaxf(h, 0.f);
    }
    __syncthreads();
    int vloc = t >> 5, e = t & 31;
    float s = b2[e];
    for (int mm = 0; mm < 128; mm++) s = fmaf(hs[vloc][mm], w2[mm*32 + e], s);
    vsb[(blockIdx.x*8 + vloc)*32 + e] = f2bf(s);
}

// ================ K45: fused MLP + relation + softmax + einsum ================
// grid (8 nblk, 64 b), 512 threads (8 waves). 4 chunks of 64 words each.
// LDS: h1b/routeB [64][264] bf16 @0 (33792) | h2b [64][264] @33792 (33792) |
//      embL [64][40] bf16 @67584 (5120) | actL f32[64] @72704 (256) |
//      wcs f32[192] @72960 (768) | redM f32[8][32] @73728 | redS @74752. = 75776 B
#define K45_LDS 75776
__global__ __launch_bounds__(512, 4) void k45(
        const unsigned short* __restrict__ vcb,
        const float* __restrict__ wcode,
        const float* __restrict__ fc1_w, const float* __restrict__ fc1_b,
        const unsigned short* __restrict__ fc2wT, const float* __restrict__ fc2_b,
        const float* __restrict__ fca_w, const float* __restrict__ fca_b,
        const unsigned short* __restrict__ fcewT, const float* __restrict__ fce_b,
        const unsigned short* __restrict__ vsb,
        float* __restrict__ out) {
    extern __shared__ char lds[];
    unsigned short* h1b    = (unsigned short*)lds;            // [64][264]
    unsigned short* routeB = (unsigned short*)lds;            // alias (h1 dead)
    unsigned short* h2b    = (unsigned short*)(lds + 33792);  // [64][264]
    unsigned short* embL   = (unsigned short*)(lds + 67584);  // [64][40]
    float* actL = (float*)(lds + 72704);                      // [64]
    float* wcs  = (float*)(lds + 72960);                      // [192]
    float* redM = (float*)(lds + 73728);                      // [8][32]
    float* redS = (float*)(lds + 74752);                      // [8][32]
    int t = threadIdx.x;
    int w = t >> 6, lane = t & 63, l31 = lane & 31, h = lane >> 5;
    int b = blockIdx.y;
    int n0 = blockIdx.x * 256;

    // hoisted invariants
    int jq = (t & 63) * 4, rb = t >> 6;
    float4 wa = *(const float4*)(fc1_w + jq);
    float4 wb = *(const float4*)(fc1_w + 256 + jq);
    float4 wc = *(const float4*)(fc1_w + 512 + jq);
    float4 bb4 = *(const float4*)(fc1_b + jq);
    int mtA = w & 1, na = (w >> 1) * 32, nb2 = na + 128;      // fc2 tiling
    float ba = fc2_b[na + l31], bbv = fc2_b[nb2 + l31];
    float be = fce_b[l31];
    int ntR = w & 1, vq = w >> 1;                             // relation tiling
    int ctE = w >> 1, ntE = w & 1;                            // einsum tiling
    size_t arowE = ((size_t)(b*128 + ctE*32 + l31))*256;

    for (int c = 0; c < 4; c++) {
        int w0 = n0 + c*64;                                   // first word of chunk
        // ---- stage wcode for 64 rows
        if (t < 192) {
            int idx = w0*3 + t;
            wcs[t] = wcode[(size_t)b*6000 + (idx < 6000 ? idx : 5999)];
        }
        __syncthreads();   // wcs ready; prev chunk's einsum (routeB reads) done
        // ---- fc1 (VALU) -> h1b
#pragma unroll
        for (int rr = 0; rr < 8; rr++) {
            int r = rb*8 + rr;
            float c0 = wcs[r*3], c1 = wcs[r*3+1], c2 = wcs[r*3+2];
            float v0 = fmaxf(fmaf(c2, wc.x, fmaf(c1, wb.x, fmaf(c0, wa.x, bb4.x))), 0.f);
            float v1 = fmaxf(fmaf(c2, wc.y, fmaf(c1, wb.y, fmaf(c0, wa.y, bb4.y))), 0.f);
            float v2 = fmaxf(fmaf(c2, wc.z, fmaf(c1, wb.z, fmaf(c0, wa.z, bb4.z))), 0.f);
            float v3 = fmaxf(fmaf(c2, wc.w, fmaf(c1, wb.w, fmaf(c0, wa.w, bb4.w))), 0.f);
            uint2 p;
            p.x = (unsigned int)f2bf(v0) | ((unsigned int)f2bf(v1) << 16);
            p.y = (unsigned int)f2bf(v2) | ((unsigned int)f2bf(v3) << 16);
            *(uint2*)(h1b + r*264 + jq) = p;
        }
        __syncthreads();
        // ---- fc2 (MFMA) -> h2b
        {
            f32x16 c0, c1;
#pragma unroll
            for (int i = 0; i < 16; i++) { c0[i] = 0.f; c1[i] = 0.f; }
#pragma unroll 4
            for (int ks = 0; ks < 16; ks++) {
                int k0 = ks*16 + h*8;
                short8 af  = *(const short8*)(h1b + (mtA*32 + l31)*264 + k0);
                short8 bfa = *(const short8*)(fc2wT + (size_t)(na  + l31)*256 + k0);
                short8 bfb = *(const short8*)(fc2wT + (size_t)(nb2 + l31)*256 + k0);
                c0 = __builtin_amdgcn_mfma_f32_32x32x16_bf16(af, bfa, c0, 0, 0, 0);
                c1 = __builtin_amdgcn_mfma_f32_32x32x16_bf16(af, bfb, c1, 0, 0, 0);
            }
#pragma unroll
            for (int i = 0; i < 16; i++) {
                int row = (i & 3) + 8*(i >> 2) + 4*h;
                h2b[(mtA*32 + row)*264 + na  + l31] = f2bf(fmaxf(c0[i] + ba, 0.f));
                h2b[(mtA*32 + row)*264 + nb2 + l31] = f2bf(fmaxf(c1[i] + bbv, 0.f));
            }
        }
        __syncthreads();
        // ---- fce (waves 0-1) + fca (waves 2-3) -> embL, actL
        if (w < 2) {
            f32x16 ce;
#pragma unroll
            for (int i = 0; i < 16; i++) ce[i] = 0.f;
#pragma unroll 4
            for (int ks = 0; ks < 16; ks++) {
                int k0 = ks*16 + h*8;
                short8 af = *(const short8*)(h2b + (w*32 + l31)*264 + k0);
                short8 bf = *(const short8*)(fcewT + (size_t)l31*256 + k0);
                ce = __builtin_amdgcn_mfma_f32_32x32x16_bf16(af, bf, ce, 0, 0, 0);
            }
#pragma unroll
            for (int i = 0; i < 16; i++) {
                int row = (i & 3) + 8*(i >> 2) + 4*h;
                embL[(w*32 + row)*40 + l31] = f2bf(ce[i] + be);
            }
        } else if (w < 4) {
            int t2 = t - 128;
            int row = t2 >> 1, half = t2 & 1;
            float s = half ? 0.f : fca_b[0];
            const unsigned short* hr = h2b + row*264 + half*128;
            const float* wp = fca_w + half*128;
#pragma unroll 8
            for (int kk = 0; kk < 64; kk++) {
                unsigned int u = *(const unsigned int*)(hr + kk*2);
                float lo = __uint_as_float(u << 16);
                float hi = __uint_as_float(u & 0xffff0000u);
                float2 wv = *(const float2*)(wp + kk*2);
                s = fmaf(lo, wv.x, s);
                s = fmaf(hi, wv.y, s);
            }
            s += __shfl_xor(s, 1);
            if (half == 0) actL[row] = 1.f / (1.f + __expf(-s));
        }
        __syncthreads();
        // ---- relation (MFMA): C[v 64][n 32] per wave; nt=w&1, vq=w>>1
        int nloc = ntR*32 + l31;
        f32x16 ra[2];
#pragma unroll
        for (int mt = 0; mt < 2; mt++)
#pragma unroll
            for (int i = 0; i < 16; i++) ra[mt][i] = 0.f;
#pragma unroll
        for (int s = 0; s < 2; s++) {
            short8 bfrag = *(const short8*)(embL + nloc*40 + s*16 + h*8);
#pragma unroll
            for (int mt = 0; mt < 2; mt++) {
                int vrow = (vq*2 + mt)*32 + l31;
                short8 afrag = *(const short8*)(vsb + vrow*32 + s*16 + h*8);
                ra[mt] = __builtin_amdgcn_mfma_f32_32x32x16_bf16(afrag, bfrag, ra[mt], 0, 0, 0);
            }
        }
        // ---- softmax over v=256 for each word col
        float mx = -1e30f;
#pragma unroll
        for (int mt = 0; mt < 2; mt++)
#pragma unroll
            for (int i = 0; i < 16; i++) mx = fmaxf(mx, ra[mt][i]);
        mx = fmaxf(mx, __shfl_xor(mx, 32));
        if (lane < 32) redM[w*32 + l31] = mx;
        __syncthreads();
#pragma unroll
        for (int q = 0; q < 4; q++) mx = fmaxf(mx, redM[(q*2 + ntR)*32 + l31]);
        float sm = 0.f;
#pragma unroll
        for (int mt = 0; mt < 2; mt++)
#pragma unroll
            for (int i = 0; i < 16; i++) {
                float e = __expf(ra[mt][i] - mx);
                ra[mt][i] = e;
                sm += e;
            }
        sm += __shfl_xor(sm, 32);
        if (lane < 32) redS[w*32 + l31] = sm;
        __syncthreads();
        sm = 0.f;
#pragma unroll
        for (int q = 0; q < 4; q++) sm += redS[(q*2 + ntR)*32 + l31];
        float scale = actL[nloc] / sm;
        // write routeB[n][v] bf16 (aliases h1b - dead after fc2)
#pragma unroll
        for (int mt = 0; mt < 2; mt++) {
#pragma unroll
            for (int rp = 0; rp < 4; rp++) {
                int vb = (vq*2 + mt)*32 + rp*8 + h*4;
                unsigned int p0 = (unsigned int)f2bf(ra[mt][rp*4+0]*scale)
                                | ((unsigned int)f2bf(ra[mt][rp*4+1]*scale) << 16);
                unsigned int p1 = (unsigned int)f2bf(ra[mt][rp*4+2]*scale)
                                | ((unsigned int)f2bf(ra[mt][rp*4+3]*scale) << 16);
                *(uint2*)(routeB + nloc*264 + vb) = make_uint2(p0, p1);
            }
        }
        __syncthreads();                       // routeB ready
        // ---- einsum (MFMA): out[c 128][n 64] = vcb[b] @ routeB^T
        {
            f32x16 cc;
#pragma unroll
            for (int i = 0; i < 16; i++) cc[i] = 0.f;
            const unsigned short* rrow = routeB + (ntE*32 + l31)*264;
#pragma unroll 4
            for (int ks = 0; ks < 16; ks++) {
                int k0 = ks*16 + h*8;
                short8 bf = *(const short8*)(rrow + k0);
                short8 a0 = *(const short8*)(vcb + arowE + k0);
                cc = __builtin_amdgcn_mfma_f32_32x32x16_bf16(a0, bf, cc, 0, 0, 0);
            }
            int ng = w0 + ntE*32 + l31;
            if (ng < NWRD) {
                float* ob = out + (size_t)b*128*NWRD + ng;
#pragma unroll
                for (int i = 0; i < 16; i++) {
                    int crow = (i & 3) + 8*(i >> 2) + 4*h;
                    ob[(size_t)(ctE*32 + crow)*NWRD] = cc[i];
                }
            }
        }
        // loop-top barrier of next chunk guards routeB/h1b reuse
    }
}

extern "C" void kernel_launch(void* const* d_in, const int* in_sizes, int n_in,
                              void* d_out, int out_size, void* d_ws, size_t ws_size,
                              hipStream_t stream) {
    const float* view_cell = (const float*)d_in[0];
    const float* v       = (const float*)d_in[1];
    const float* w2c_w1  = (const float*)d_in[2];
    const float* w2c_b1  = (const float*)d_in[3];
    const float* w2c_w2  = (const float*)d_in[4];
    const float* w2c_b2  = (const float*)d_in[5];
    const float* fc1_w   = (const float*)d_in[6];
    const float* fc1_b   = (const float*)d_in[7];
    const float* fc2_w   = (const float*)d_in[8];
    const float* fc2_b   = (const float*)d_in[9];
    const float* fca_w   = (const float*)d_in[10];
    const float* fca_b   = (const float*)d_in[11];
    const float* fce_w   = (const float*)d_in[12];
    const float* fce_b   = (const float*)d_in[13];
    const float* vse_w1  = (const float*)d_in[14];
    const float* vse_b1  = (const float*)d_in[15];
    const float* vse_w2  = (const float*)d_in[16];
    const float* vse_b2  = (const float*)d_in[17];
    float* ws    = (float*)d_ws;
    unsigned short* fc2wT = (unsigned short*)(ws + WS_FC2WT);
    float* wcode = ws + WS_WCODE;
    unsigned short* vsb   = (unsigned short*)(ws + WS_VSB);
    unsigned short* vcb   = (unsigned short*)(ws + WS_VCB);
    unsigned short* fcewT = (unsigned short*)(ws + WS_FCEWT);
    unsigned short* h0b   = (unsigned short*)(ws + WS_H0B);
    unsigned short* w2T   = (unsigned short*)(ws + WS_W2T);
    float* out   = (float*)d_out;

    k0_vcb<<<1024, 256, 0, stream>>>(view_cell, vcb);
    k1_h0<<<64, 512, 0, stream>>>(v, w2c_w1, w2c_b1, h0b);
    {
        dim3 gt(94, 8);
        k2t_w2<<<gt, 256, 0, stream>>>(w2c_w2, w2T);
    }
    k2_gemm<<<47, 512, 0, stream>>>(h0b, w2T, w2c_b2, wcode);
    k0w_fc2t<<<16, 256, 0, stream>>>(fc2_w, fc2wT);
    k0e_fcet<<<1, 256, 0, stream>>>(fce_w, fcewT);
    k3_vs<<<32, 256, 0, stream>>>(vse_w1, vse_b1, vse_w2, vse_b2, vsb);
    (void)hipFuncSetAttribute((const void*)k45,
                              hipFuncAttributeMaxDynamicSharedMemorySize, K45_LDS);
    dim3 g45(8, 64);
    k45<<<g45, 512, K45_LDS, stream>>>(vcb, wcode, fc1_w, fc1_b, fc2wT, fc2_b,
                                       fca_w, fca_b, fcewT, fce_b, vsb, out);
}

// Round 6
// 243.910 us; speedup vs baseline: 4.1049x; 1.0398x over previous
//
#include <hip/hip_runtime.h>
#include <hip/hip_bf16.h>
#include <math.h>

#define NWRD 2000
#define BB 64
#define CS 128
#define VV 256

typedef __attribute__((ext_vector_type(8)))  short short8;   // 8 bf16 (4 VGPRs)
typedef __attribute__((ext_vector_type(16))) float f32x16;   // MFMA 32x32 acc

// workspace layout (float offsets)
#define WS_FC2WT 0                         // 256*256 bf16
#define WS_WCODE (WS_FC2WT + 32768)        // 64*6000 f32  ([b][n*3+c])
#define WS_VSB   (WS_WCODE + 384000)       // 256*32 bf16
#define WS_W2T   (WS_VSB + 4096)           // 6000*512 bf16 (1536000 f32-eq)
#define WS_VCB   (WS_W2T + 1536000)        // 64*128*256 bf16
#define WS_FCEWT (WS_VCB + 1048576)        // 32*256 bf16
#define WS_H0B   (WS_FCEWT + 4096)         // 64*512 bf16
#define WS_FCAWB (WS_H0B + 16384)          // 32*256 bf16 (col0=fca_w, rest 0)

__device__ __forceinline__ unsigned short f2bf(float x) {
    unsigned int u = __float_as_uint(x);
    u += 0x7fffu + ((u >> 16) & 1u);       // round-to-nearest-even
    return (unsigned short)(u >> 16);
}

// ================ KPREP: all independent prep jobs in ONE launch ================
// blocks [0,1024): vcb convert | [1024,1776): w2T | [1776,1904): h0b |
// [1904,1936): vsb | [1936,1952): fc2wT | 1952: fcewT+fcawB
#define PREP_A 1024
#define PREP_B (PREP_A + 752)
#define PREP_C (PREP_B + 128)
#define PREP_D (PREP_C + 32)
#define PREP_E (PREP_D + 16)
#define PREP_N (PREP_E + 1)
__global__ __launch_bounds__(256) void kprep(
        const float* __restrict__ vc, unsigned short* __restrict__ vcb,
        const float* __restrict__ w2, unsigned short* __restrict__ w2T,
        const float* __restrict__ v, const float* __restrict__ w2c_w1,
        const float* __restrict__ w2c_b1, unsigned short* __restrict__ h0b,
        const float* __restrict__ vse_w1, const float* __restrict__ vse_b1,
        const float* __restrict__ vse_w2, const float* __restrict__ vse_b2,
        unsigned short* __restrict__ vsb,
        const float* __restrict__ fc2_w, unsigned short* __restrict__ fc2wT,
        const float* __restrict__ fce_w, unsigned short* __restrict__ fcewT,
        const float* __restrict__ fca_w, unsigned short* __restrict__ fcawB) {
    __shared__ unsigned short smem[9216];   // unioned scratch (18.4 KB)
    int bid = blockIdx.x, t = threadIdx.x;
    if (bid < PREP_A) {
        // ---- view_cell f32 -> bf16
        int i = (bid * 256 + t) * 8;
        float4 f0 = *(const float4*)(vc + i);
        float4 f1 = *(const float4*)(vc + i + 4);
        union { short8 v8; unsigned short u[8]; } o;
        o.u[0] = f2bf(f0.x); o.u[1] = f2bf(f0.y); o.u[2] = f2bf(f0.z); o.u[3] = f2bf(f0.w);
        o.u[4] = f2bf(f1.x); o.u[5] = f2bf(f1.y); o.u[6] = f2bf(f1.z); o.u[7] = f2bf(f1.w);
        *(short8*)(vcb + i) = o.v8;
    } else if (bid < PREP_B) {
        // ---- w2 (512x6000 f32) -> w2T (6000x512 bf16)
        unsigned short (*tile)[66] = (unsigned short(*)[66])smem;
        int b2 = bid - PREP_A;
        int n0 = (b2 % 94) * 64, k0 = (b2 / 94) * 64;
        int nl = t & 63, kb = (t >> 6) * 16;
        int nc = (n0 + nl) < 6000 ? (n0 + nl) : 5999;
#pragma unroll
        for (int i = 0; i < 16; i++)
            tile[nl][kb + i] = f2bf(w2[(size_t)(k0 + kb + i)*6000 + nc]);
        __syncthreads();
        int kl = t & 63, nb = (t >> 6) * 16;
#pragma unroll
        for (int i = 0; i < 16; i++) {
            int nn = n0 + nb + i;
            if (nn < 6000) w2T[(size_t)nn*512 + k0 + kl] = tile[nb + i][kl];
        }
    } else if (bid < PREP_C) {
        // ---- h0b = relu(v @ w2c_w1 + b1) bf16 row-major
        int c = bid - PREP_B;
        int b = c >> 1, j = (c & 1)*256 + t;
        float s = w2c_b1[j];
#pragma unroll
        for (int k = 0; k < 7; k++) s = fmaf(v[b*7 + k], w2c_w1[k*512 + j], s);
        h0b[b*512 + j] = f2bf(fmaxf(s, 0.f));
    } else if (bid < PREP_D) {
        // ---- vs MLP -> bf16
        float* hs = (float*)smem;   // [8][128]
        int blk = bid - PREP_C;
        int m = t & 127, half = t >> 7;
#pragma unroll
        for (int q = 0; q < 4; q++) {
            int vloc = half*4 + q;
            int vv = blk*8 + vloc;
            float x = (2.f/15.f)*(float)(vv >> 4) - 1.f;
            float y = (2.f/15.f)*(float)(vv & 15) - 1.f;
            float h = vse_b1[m] + x*vse_w1[m] + y*vse_w1[128 + m];
            hs[vloc*128 + m] = fmaxf(h, 0.f);
        }
        __syncthreads();
        int vloc = t >> 5, e = t & 31;
        float s = vse_b2[e];
        for (int mm = 0; mm < 128; mm++) s = fmaf(hs[vloc*128 + mm], vse_w2[mm*32 + e], s);
        vsb[(blk*8 + vloc)*32 + e] = f2bf(s);
    } else if (bid < PREP_E) {
        // ---- fc2_w -> fc2wT (n-major bf16)
        unsigned short (*tile)[72] = (unsigned short(*)[72])smem;
        int b2 = bid - PREP_D;
        int k0t = (b2 >> 2) * 64, n0t = (b2 & 3) * 64;
        int nl = t & 63, kb = (t >> 6) * 16;
#pragma unroll
        for (int i = 0; i < 16; i++)
            tile[kb + i][nl] = f2bf(fc2_w[(size_t)(k0t + kb + i)*256 + n0t + nl]);
        __syncthreads();
        int kl = t & 63, nb = (t >> 6) * 16;
#pragma unroll
        for (int i = 0; i < 16; i++)
            fc2wT[(size_t)(n0t + nb + i)*256 + k0t + kl] = tile[kl][nb + i];
    } else {
        // ---- fcewT (32x256 bf16, e-major) + fcawB (col0 = fca_w, rest 0)
        int e = t & 31, kb = (t >> 5) * 32;
        unsigned short tmp[32];
#pragma unroll
        for (int i = 0; i < 32; i++) tmp[i] = f2bf(fce_w[(size_t)(kb + i)*32 + e]);
#pragma unroll
        for (int i = 0; i < 4; i++)
            *(short8*)(fcewT + (size_t)e*256 + kb + i*8) = *(short8*)(tmp + i*8);
#pragma unroll
        for (int i = 0; i < 32; i++)
            fcawB[(size_t)e*256 + kb + i] = (e == 0) ? f2bf(fca_w[kb + i]) : (unsigned short)0;
    }
}

// ---------------- K2: wcode = h0 @ w2 + b2 via MFMA (M=64, N=6000, K=512)
__global__ __launch_bounds__(512) void k2_gemm(const unsigned short* __restrict__ h0b,
        const unsigned short* __restrict__ w2T, const float* __restrict__ b2,
        float* __restrict__ wcode) {
    int t = threadIdx.x;
    int w = t >> 6, lane = t & 63, l31 = lane & 31, h = lane >> 5;
    int mt = w & 1, nt = w >> 1;
    int n = blockIdx.x*128 + nt*32 + l31;
    int nc = n < 6000 ? n : 5999;
    f32x16 a0v, a1v;
#pragma unroll
    for (int i = 0; i < 16; i++) { a0v[i] = 0.f; a1v[i] = 0.f; }
#pragma unroll 8
    for (int ks = 0; ks < 16; ks++) {
        int k0 = ks*16 + h*8;
        short8 af0 = *(const short8*)(h0b + (mt*32 + l31)*512 + k0);
        short8 bf0 = *(const short8*)(w2T + (size_t)nc*512 + k0);
        a0v = __builtin_amdgcn_mfma_f32_32x32x16_bf16(af0, bf0, a0v, 0, 0, 0);
        short8 af1 = *(const short8*)(h0b + (mt*32 + l31)*512 + k0 + 256);
        short8 bf1 = *(const short8*)(w2T + (size_t)nc*512 + k0 + 256);
        a1v = __builtin_amdgcn_mfma_f32_32x32x16_bf16(af1, bf1, a1v, 0, 0, 0);
    }
    if (n < 6000) {
        float bias = b2[n];
#pragma unroll
        for (int i = 0; i < 16; i++) {
            int row = (i & 3) + 8*(i >> 2) + 4*h;
            wcode[(size_t)(mt*32 + row)*6000 + n] = a0v[i] + a1v[i] + bias;
        }
    }
}

// ================ K45: fused MLP + relation + softmax + einsum ================
// grid (8 nblk, 64 b), 512 threads (8 waves), 4 chunks of 64 words.
// LDS: h1b [64][264] @0 | h2b/routeB [64][264] @33792 | embL [64][40] @67584 |
//      actL[64] @72704 | wcsAll[768] @72960 | redS[8][32] @76032. total 77056 B
#define K45_LDS 77056
__global__ __launch_bounds__(512, 4) void k45(
        const unsigned short* __restrict__ vcb,
        const float* __restrict__ wcode,
        const float* __restrict__ fc1_w, const float* __restrict__ fc1_b,
        const unsigned short* __restrict__ fc2wT, const float* __restrict__ fc2_b,
        const float* __restrict__ fca_b_p,
        const unsigned short* __restrict__ fcawB,
        const unsigned short* __restrict__ fcewT, const float* __restrict__ fce_b,
        const unsigned short* __restrict__ vsb,
        float* __restrict__ out) {
    extern __shared__ char lds[];
    unsigned short* h1b    = (unsigned short*)lds;            // [64][264]
    unsigned short* h2b    = (unsigned short*)(lds + 33792);  // [64][264]
    unsigned short* routeB = h2b;                             // alias (h2 dead by write time)
    unsigned short* embL   = (unsigned short*)(lds + 67584);  // [64][40]
    float* actL   = (float*)(lds + 72704);                    // [64]
    float* wcsAll = (float*)(lds + 72960);                    // [768]
    float* redS   = (float*)(lds + 76032);                    // [8][32]
    int t = threadIdx.x;
    int w = t >> 6, lane = t & 63, l31 = lane & 31, h = lane >> 5;
    int b = blockIdx.y;
    int n0 = blockIdx.x * 256;

    // ---- stage all 4 chunks' wcode once (768 f32)
    {
        const float* wb = wcode + (size_t)b*6000;
        int i0 = n0*3 + t;
        wcsAll[t] = wb[i0 < 6000 ? i0 : 5999];
        if (t < 256) {
            int i1 = n0*3 + 512 + t;
            wcsAll[512 + t] = wb[i1 < 6000 ? i1 : 5999];
        }
    }
    // hoisted invariants
    int jq = (t & 63) * 4;
    float4 wa  = *(const float4*)(fc1_w + jq);
    float4 wb4 = *(const float4*)(fc1_w + 256 + jq);
    float4 wc  = *(const float4*)(fc1_w + 512 + jq);
    float4 bb4 = *(const float4*)(fc1_b + jq);
    int mtA = w & 1, na = (w >> 1) * 32, nb2 = na + 128;      // fc2 tiling
    float ba = fc2_b[na + l31], bbv = fc2_b[nb2 + l31];
    float be = fce_b[l31];
    float fcab = fca_b_p[0];
    int ntR = w & 1, vq = w >> 1;                             // relation tiling
    int ctE = w >> 1, ntE = w & 1;                            // einsum tiling
    size_t arowE = ((size_t)(b*128 + ctE*32 + l31))*256;
    __syncthreads();

    for (int c = 0; c < 4; c++) {
        int w0 = n0 + c*64;
        // ---- fc1 (VALU) -> h1b   (overlaps prev chunk's einsum)
#pragma unroll
        for (int rr = 0; rr < 8; rr++) {
            int r = w*8 + rr;
            const float* wr = wcsAll + (c*64 + r)*3;
            float c0 = wr[0], c1 = wr[1], c2 = wr[2];
            float v0 = fmaxf(fmaf(c2, wc.x, fmaf(c1, wb4.x, fmaf(c0, wa.x, bb4.x))), 0.f);
            float v1 = fmaxf(fmaf(c2, wc.y, fmaf(c1, wb4.y, fmaf(c0, wa.y, bb4.y))), 0.f);
            float v2 = fmaxf(fmaf(c2, wc.z, fmaf(c1, wb4.z, fmaf(c0, wa.z, bb4.z))), 0.f);
            float v3 = fmaxf(fmaf(c2, wc.w, fmaf(c1, wb4.w, fmaf(c0, wa.w, bb4.w))), 0.f);
            uint2 p;
            p.x = (unsigned int)f2bf(v0) | ((unsigned int)f2bf(v1) << 16);
            p.y = (unsigned int)f2bf(v2) | ((unsigned int)f2bf(v3) << 16);
            *(uint2*)(h1b + r*264 + jq) = p;
        }
        __syncthreads();   // B1: h1b ready; prev einsum's routeB reads done
        // ---- fc2 (MFMA) -> h2b
        {
            f32x16 c0, c1;
#pragma unroll
            for (int i = 0; i < 16; i++) { c0[i] = 0.f; c1[i] = 0.f; }
#pragma unroll 4
            for (int ks = 0; ks < 16; ks++) {
                int k0 = ks*16 + h*8;
                short8 af  = *(const short8*)(h1b + (mtA*32 + l31)*264 + k0);
                short8 bfa = *(const short8*)(fc2wT + (size_t)(na  + l31)*256 + k0);
                short8 bfb = *(const short8*)(fc2wT + (size_t)(nb2 + l31)*256 + k0);
                c0 = __builtin_amdgcn_mfma_f32_32x32x16_bf16(af, bfa, c0, 0, 0, 0);
                c1 = __builtin_amdgcn_mfma_f32_32x32x16_bf16(af, bfb, c1, 0, 0, 0);
            }
#pragma unroll
            for (int i = 0; i < 16; i++) {
                int row = (i & 3) + 8*(i >> 2) + 4*h;
                h2b[(mtA*32 + row)*264 + na  + l31] = f2bf(fmaxf(c0[i] + ba, 0.f));
                h2b[(mtA*32 + row)*264 + nb2 + l31] = f2bf(fmaxf(c1[i] + bbv, 0.f));
            }
        }
        __syncthreads();   // B2
        // ---- fce (waves 0-1) + fca-as-MFMA (waves 2-3) -> embL, actL
        if (w < 2) {
            f32x16 ce;
#pragma unroll
            for (int i = 0; i < 16; i++) ce[i] = 0.f;
#pragma unroll 4
            for (int ks = 0; ks < 16; ks++) {
                int k0 = ks*16 + h*8;
                short8 af = *(const short8*)(h2b + (w*32 + l31)*264 + k0);
                short8 bf = *(const short8*)(fcewT + (size_t)l31*256 + k0);
                ce = __builtin_amdgcn_mfma_f32_32x32x16_bf16(af, bf, ce, 0, 0, 0);
            }
#pragma unroll
            for (int i = 0; i < 16; i++) {
                int row = (i & 3) + 8*(i >> 2) + 4*h;
                embL[(w*32 + row)*40 + l31] = f2bf(ce[i] + be);
            }
        } else if (w < 4) {
            int m = w - 2;
            f32x16 ca;
#pragma unroll
            for (int i = 0; i < 16; i++) ca[i] = 0.f;
#pragma unroll 4
            for (int ks = 0; ks < 16; ks++) {
                int k0 = ks*16 + h*8;
                short8 af = *(const short8*)(h2b + (m*32 + l31)*264 + k0);
                short8 bf = *(const short8*)(fcawB + (size_t)l31*256 + k0);
                ca = __builtin_amdgcn_mfma_f32_32x32x16_bf16(af, bf, ca, 0, 0, 0);
            }
            if (l31 == 0) {
#pragma unroll
                for (int i = 0; i < 16; i++) {
                    int row = (i & 3) + 8*(i >> 2) + 4*h;
                    actL[m*32 + row] = 1.f / (1.f + __expf(-(ca[i] + fcab)));
                }
            }
        }
        __syncthreads();   // B3: embL, actL ready
        // ---- relation (MFMA): wave = (n-tile ntR, v-quarter vq)
        int nloc = ntR*32 + l31;
        f32x16 ra[2];
#pragma unroll
        for (int mt = 0; mt < 2; mt++)
#pragma unroll
            for (int i = 0; i < 16; i++) ra[mt][i] = 0.f;
#pragma unroll
        for (int s = 0; s < 2; s++) {
            short8 bfrag = *(const short8*)(embL + nloc*40 + s*16 + h*8);
#pragma unroll
            for (int mt = 0; mt < 2; mt++) {
                int vrow = (vq*2 + mt)*32 + l31;
                short8 afrag = *(const short8*)(vsb + vrow*32 + s*16 + h*8);
                ra[mt] = __builtin_amdgcn_mfma_f32_32x32x16_bf16(afrag, bfrag, ra[mt], 0, 0, 0);
            }
        }
        // ---- softmax over v=256 (no max-sub: logits are tiny; exact same math)
        float sm = 0.f;
#pragma unroll
        for (int mt = 0; mt < 2; mt++)
#pragma unroll
            for (int i = 0; i < 16; i++) {
                float e = __expf(ra[mt][i]);
                ra[mt][i] = e;
                sm += e;
            }
        sm += __shfl_xor(sm, 32);
        if (lane < 32) redS[w*32 + l31] = sm;
        __syncthreads();   // B4
        sm = 0.f;
#pragma unroll
        for (int q = 0; q < 4; q++) sm += redS[(q*2 + ntR)*32 + l31];
        float scale = actL[nloc] / sm;
        // ---- routeB[n][v] bf16 (aliases h2b - dead after fce/fca)
#pragma unroll
        for (int mt = 0; mt < 2; mt++) {
#pragma unroll
            for (int rp = 0; rp < 4; rp++) {
                int vb = (vq*2 + mt)*32 + rp*8 + h*4;
                unsigned int p0 = (unsigned int)f2bf(ra[mt][rp*4+0]*scale)
                                | ((unsigned int)f2bf(ra[mt][rp*4+1]*scale) << 16);
                unsigned int p1 = (unsigned int)f2bf(ra[mt][rp*4+2]*scale)
                                | ((unsigned int)f2bf(ra[mt][rp*4+3]*scale) << 16);
                *(uint2*)(routeB + nloc*264 + vb) = make_uint2(p0, p1);
            }
        }
        __syncthreads();   // B5: routeB ready
        // ---- einsum (MFMA): out[c 128][n 64] = vcb[b] @ routeB^T
        {
            f32x16 cc;
#pragma unroll
            for (int i = 0; i < 16; i++) cc[i] = 0.f;
            const unsigned short* rrow = routeB + (ntE*32 + l31)*264;
#pragma unroll 4
            for (int ks = 0; ks < 16; ks++) {
                int k0 = ks*16 + h*8;
                short8 bf = *(const short8*)(rrow + k0);
                short8 a0 = *(const short8*)(vcb + arowE + k0);
                cc = __builtin_amdgcn_mfma_f32_32x32x16_bf16(a0, bf, cc, 0, 0, 0);
            }
            int ng = w0 + ntE*32 + l31;
            if (ng < NWRD) {
                float* ob = out + (size_t)b*128*NWRD + ng;
#pragma unroll
                for (int i = 0; i < 16; i++) {
                    int crow = (i & 3) + 8*(i >> 2) + 4*h;
                    ob[(size_t)(ctE*32 + crow)*NWRD] = cc[i];
                }
            }
        }
        // no loop-top barrier: next fc1 writes h1b (not routeB); B1 guards fc2
    }
}

extern "C" void kernel_launch(void* const* d_in, const int* in_sizes, int n_in,
                              void* d_out, int out_size, void* d_ws, size_t ws_size,
                              hipStream_t stream) {
    const float* view_cell = (const float*)d_in[0];
    const float* v       = (const float*)d_in[1];
    const float* w2c_w1  = (const float*)d_in[2];
    const float* w2c_b1  = (const float*)d_in[3];
    const float* w2c_w2  = (const float*)d_in[4];
    const float* w2c_b2  = (const float*)d_in[5];
    const float* fc1_w   = (const float*)d_in[6];
    const float* fc1_b   = (const float*)d_in[7];
    const float* fc2_w   = (const float*)d_in[8];
    const float* fc2_b   = (const float*)d_in[9];
    const float* fca_w   = (const float*)d_in[10];
    const float* fca_b   = (const float*)d_in[11];
    const float* fce_w   = (const float*)d_in[12];
    const float* fce_b   = (const float*)d_in[13];
    const float* vse_w1  = (const float*)d_in[14];
    const float* vse_b1  = (const float*)d_in[15];
    const float* vse_w2  = (const float*)d_in[16];
    const float* vse_b2  = (const float*)d_in[17];
    float* ws    = (float*)d_ws;
    unsigned short* fc2wT = (unsigned short*)(ws + WS_FC2WT);
    float* wcode = ws + WS_WCODE;
    unsigned short* vsb   = (unsigned short*)(ws + WS_VSB);
    unsigned short* w2T   = (unsigned short*)(ws + WS_W2T);
    unsigned short* vcb   = (unsigned short*)(ws + WS_VCB);
    unsigned short* fcewT = (unsigned short*)(ws + WS_FCEWT);
    unsigned short* h0b   = (unsigned short*)(ws + WS_H0B);
    unsigned short* fcawB = (unsigned short*)(ws + WS_FCAWB);
    float* out   = (float*)d_out;

    kprep<<<PREP_N, 256, 0, stream>>>(view_cell, vcb, w2c_w2, w2T,
                                      v, w2c_w1, w2c_b1, h0b,
                                      vse_w1, vse_b1, vse_w2, vse_b2, vsb,
                                      fc2_w, fc2wT, fce_w, fcewT, fca_w, fcawB);
    k2_gemm<<<47, 512, 0, stream>>>(h0b, w2T, w2c_b2, wcode);
    (void)hipFuncSetAttribute((const void*)k45,
                              hipFuncAttributeMaxDynamicSharedMemorySize, K45_LDS);
    dim3 g45(8, 64);
    k45<<<g45, 512, K45_LDS, stream>>>(vcb, wcode, fc1_w, fc1_b, fc2wT, fc2_b,
                                       fca_b, fcawB, fcewT, fce_b, vsb, out);
}